// Round 1
// baseline (2499.883 us; speedup 1.0000x reference)
//
#include <hip/hip_runtime.h>
#include <math.h>

// ---------------- sizes ----------------
#define B32   32
#define OCLS  102
#define NCAPS 2592
#define DIN   8
#define DOUT  16

// ws offsets (in floats); all multiples of 4 -> 16B aligned
#define OFF_FEAT   0u               // 32*256*34*36 = 10,027,008
#define OFF_C1WT   10027008u        // 363*256      =     92,928
#define OFF_PCWT   10119936u        // 20736*256    =  5,308,416
#define OFF_PCP    15428352u        // 8*32*81*256  =  5,308,416
#define OFF_PC2    20736768u        // 32*81*256    =    663,552
#define OFF_U2     21400320u        // 32*2592*8
#define OFF_U3     22063872u        // 32*8*2592
#define OFF_C3     22727424u        // 102*32*2592  =  8,460,288
#define OFF_S      31187712u        // 32*102*16    =     52,224
#define OFF_V0     31239936u
#define OFF_V1     31292160u
#define OFF_VS     31344384u
#define OFF_H1     31396608u        // 32*512
#define OFF_H2T    31412992u        // 1024*32

// ---------------- weight transpose [CO][K] -> [K][CO] ----------------
__global__ void k_wtrans(const float* __restrict__ in, float* __restrict__ out,
                         int CO, int K) {
  __shared__ float t[64][65];
  int kb = blockIdx.x * 64, cb = blockIdx.y * 64;
  int tx = threadIdx.x & 63, ty = threadIdx.x >> 6;
  for (int r = ty; r < 64; r += 4) {
    int co = cb + r, k = kb + tx;
    t[r][tx] = (k < K) ? in[(size_t)co * K + k] : 0.f;
  }
  __syncthreads();
  for (int r = ty; r < 64; r += 4) {
    int k = kb + r, co = cb + tx;
    if (k < K) out[(size_t)k * CO + co] = t[tx][r];
  }
}

// ---------------- conv1 11x11 s3 + bias + relu ----------------
// block = (b,ho), 256 threads = co. OFF=0: wo 0..16, OFF=3: wo 17..33.
// input rows are wave-uniform loads (broadcast); weights coalesced from c1wT.
template <int OFF>
__global__ __launch_bounds__(256) void k_conv1(const float* __restrict__ x,
                                               const float* __restrict__ c1wT,
                                               const float* __restrict__ bias,
                                               float* __restrict__ feat) {
  int bx = blockIdx.x;
  int ho = bx % 34, b = bx / 34;
  int co = threadIdx.x;
  const int wobase = (OFF == 0) ? 0 : 17;
  const int a0 = (OFF == 0) ? 0 : 48;

  float bv = bias[co];
  float acc[17];
#pragma unroll
  for (int w = 0; w < 17; ++w) acc[w] = bv;

#pragma unroll 1
  for (int ci = 0; ci < 3; ++ci) {
#pragma unroll 1
    for (int kh = 0; kh < 11; ++kh) {
      int h = ho * 3 + kh;
      const float4* xr = (const float4*)(x + ((b * 3 + ci) * 112 + h) * 112 + a0);
      float w_[11];
#pragma unroll
      for (int kw = 0; kw < 11; ++kw)
        w_[kw] = c1wT[((ci * 11 + kh) * 11 + kw) * 256 + co];
      float rr[64];
#pragma unroll
      for (int q = 0; q < 16; ++q) {
        float4 v = xr[q];
        rr[4 * q] = v.x; rr[4 * q + 1] = v.y; rr[4 * q + 2] = v.z; rr[4 * q + 3] = v.w;
      }
#pragma unroll
      for (int w = 0; w < 17; ++w)
#pragma unroll
        for (int kw = 0; kw < 11; ++kw)
          acc[w] += w_[kw] * rr[3 * w + kw + OFF];
    }
  }
  // stage through LDS so global stores are coalesced runs
  __shared__ float ot[256 * 17];
#pragma unroll
  for (int w = 0; w < 17; ++w) ot[co * 17 + w] = fmaxf(acc[w], 0.f);
  __syncthreads();
  for (int it = 0; it < 17; ++it) {
    int idx = it * 256 + threadIdx.x;
    int c2 = idx / 17, w2 = idx - c2 * 17;
    feat[((b * 256 + c2) * 34 + ho) * 36 + wobase + w2] = ot[idx];
  }
}

// ---------------- primary caps conv 9x9 s3 (no relu, bias later) ----------------
// block = (ho, bq(2b), cc(32ci)), 256 threads = co; partials into pcp.
__global__ __launch_bounds__(256) void k_pc(const float* __restrict__ feat,
                                            const float* __restrict__ pcwT,
                                            float* __restrict__ pcp) {
  int bx = blockIdx.x;
  int ho = bx % 9;
  int bq = (bx / 9) & 15;
  int cc = bx / 144;
  int co = threadIdx.x;
  int b0 = bq * 2;

  float acc[2][9];
#pragma unroll
  for (int bi = 0; bi < 2; ++bi)
#pragma unroll
    for (int wo = 0; wo < 9; ++wo) acc[bi][wo] = 0.f;

#pragma unroll 1
  for (int cil = 0; cil < 32; ++cil) {
    int ci = cc * 32 + cil;
#pragma unroll 1
    for (int kh = 0; kh < 9; ++kh) {
      int h = ho * 3 + kh;
      const float4* r0 = (const float4*)(feat + ((b0 * 256 + ci) * 34 + h) * 36);
      const float4* r1 = (const float4*)(feat + (((b0 + 1) * 256 + ci) * 34 + h) * 36);
      float ra[36], rb[36];
#pragma unroll
      for (int q = 0; q < 9; ++q) {
        float4 v = r0[q];
        ra[4 * q] = v.x; ra[4 * q + 1] = v.y; ra[4 * q + 2] = v.z; ra[4 * q + 3] = v.w;
        float4 u = r1[q];
        rb[4 * q] = u.x; rb[4 * q + 1] = u.y; rb[4 * q + 2] = u.z; rb[4 * q + 3] = u.w;
      }
      const float* wrow = pcwT + ((ci * 9 + kh) * 9) * 256 + co;
#pragma unroll
      for (int kw = 0; kw < 9; ++kw) {
        float wv = wrow[kw * 256];
#pragma unroll
        for (int wo = 0; wo < 9; ++wo) {
          acc[0][wo] += wv * ra[wo * 3 + kw];
          acc[1][wo] += wv * rb[wo * 3 + kw];
        }
      }
    }
  }
#pragma unroll
  for (int bi = 0; bi < 2; ++bi)
#pragma unroll
    for (int wo = 0; wo < 9; ++wo) {
      int p = ho * 9 + wo;
      pcp[((cc * 32 + (b0 + bi)) * 81 + p) * 256 + co] = acc[bi][wo];
    }
}

// sum 8 ci-chunk partials + bias
__global__ void k_pcreduce(const float* __restrict__ pcp,
                           const float* __restrict__ pcb,
                           float* __restrict__ pc2) {
  int i = blockIdx.x * 256 + threadIdx.x;  // < 663552
  float s = pcb[i & 255];
#pragma unroll
  for (int c = 0; c < 8; ++c) s += pcp[c * 663552 + i];
  pc2[i] = s;
}

// squash u (dim 8); write u2[b][n][i] and u3[b][i][n]
__global__ void k_squash(const float* __restrict__ pc2,
                         float* __restrict__ u2, float* __restrict__ u3) {
  int t = blockIdx.x * 256 + threadIdx.x;  // < 82944
  int b = t / 2592, n = t - b * 2592;
  float v[8];
  float sq = 0.f;
#pragma unroll
  for (int i = 0; i < 8; ++i) {
    int f = n * 8 + i;
    int co = f / 81, p = f - co * 81;
    v[i] = pc2[(b * 81 + p) * 256 + co];
    sq += v[i] * v[i];
  }
  float sc = (sq / (1.f + sq)) / sqrtf(sq + 1e-8f);
#pragma unroll
  for (int i = 0; i < 8; ++i) {
    float uv = v[i] * sc;
    u2[t * 8 + i] = uv;
    u3[(b * 8 + i) * 2592 + n] = uv;
  }
}

// ---------------- routing kernel A: logits + softmax -> c3[o][b][n] ----------------
// block = n-tile of 3; 128 threads, thread = class o (o<102 active).
// bb[b,o,n] = xhat(b,o,n,:) . vsum(b,o,:) ; c = softmax over o (no max-sub: |bb|<0.5)
__global__ __launch_bounds__(128) void k_A(const float* __restrict__ W,
                                           const float* __restrict__ u2,
                                           const float* __restrict__ vsum,
                                           float* __restrict__ c3) {
  __shared__ float red[102 * 33];
  __shared__ float r2[4 * 33];
  __shared__ float ctile[102 * 33 * 3];
  int o = threadIdx.x;
  int nb = blockIdx.x;  // 864

  for (int nt = 0; nt < 3; ++nt) {
    int n = nb * 3 + nt;
    if (o < 102) {
      float4 wf[32];
      const float4* wp = (const float4*)(W + (size_t)(o * 2592 + n) * 128);
#pragma unroll
      for (int q = 0; q < 32; ++q) wf[q] = wp[q];
#pragma unroll 1
      for (int b = 0; b < 32; ++b) {
        float vr[16];
        {
          const float4* vp = (const float4*)(vsum + (b * 102 + o) * 16);
          float4 q0 = vp[0], q1 = vp[1], q2 = vp[2], q3 = vp[3];
          vr[0] = q0.x; vr[1] = q0.y; vr[2] = q0.z; vr[3] = q0.w;
          vr[4] = q1.x; vr[5] = q1.y; vr[6] = q1.z; vr[7] = q1.w;
          vr[8] = q2.x; vr[9] = q2.y; vr[10] = q2.z; vr[11] = q2.w;
          vr[12] = q3.x; vr[13] = q3.y; vr[14] = q3.z; vr[15] = q3.w;
        }
        float t[8] = {0, 0, 0, 0, 0, 0, 0, 0};
#pragma unroll
        for (int d = 0; d < 16; ++d) {
          float vd = vr[d];
          float4 wa = wf[2 * d], wb = wf[2 * d + 1];
          t[0] += wa.x * vd; t[1] += wa.y * vd; t[2] += wa.z * vd; t[3] += wa.w * vd;
          t[4] += wb.x * vd; t[5] += wb.y * vd; t[6] += wb.z * vd; t[7] += wb.w * vd;
        }
        const float4* up = (const float4*)(u2 + (size_t)(b * 2592 + n) * 8);
        float4 ua = up[0], ub = up[1];
        float dlt = t[0] * ua.x + t[1] * ua.y + t[2] * ua.z + t[3] * ua.w +
                    t[4] * ub.x + t[5] * ub.y + t[6] * ub.z + t[7] * ub.w;
        red[o * 33 + b] = __expf(dlt);
      }
    }
    __syncthreads();
    {
      int bb = threadIdx.x & 31, g = threadIdx.x >> 5;
      float ps = 0.f;
      int oend = (g * 26 + 26 < 102) ? g * 26 + 26 : 102;
      for (int oo = g * 26; oo < oend; ++oo) ps += red[oo * 33 + bb];
      r2[g * 33 + bb] = ps;
    }
    __syncthreads();
    if (threadIdx.x < 32) {
      int bb = threadIdx.x;
      r2[bb] = 1.0f / (r2[bb] + r2[33 + bb] + r2[66 + bb] + r2[99 + bb]);
    }
    __syncthreads();
    if (o < 102) {
#pragma unroll 1
      for (int b = 0; b < 32; ++b)
        ctile[(o * 33 + b) * 3 + nt] = red[o * 33 + b] * r2[b];
    }
    __syncthreads();
  }
  // coop write c3[o][b][n0..n0+2]
  for (int it = 0; it < 26; ++it) {
    int idx = it * 128 + threadIdx.x;
    if (idx < 3264) {
      int oo = idx >> 5, bb = idx & 31;
      float* dst = c3 + (size_t)(oo * 32 + bb) * 2592 + nb * 3;
      dst[0] = ctile[(oo * 33 + bb) * 3 + 0];
      dst[1] = ctile[(oo * 33 + bb) * 3 + 1];
      dst[2] = ctile[(oo * 33 + bb) * 3 + 2];
    }
  }
}

// ---------------- routing kernel B: s[b,o,d] += sum_n c * xhat ----------------
// block = (o, n-span 256); thread = (dq, lane) -> lane owns 4 consecutive n.
template <bool HASC>
__global__ __launch_bounds__(256) void k_B(const float* __restrict__ W,
                                           const float* __restrict__ u3g,
                                           const float* __restrict__ c3,
                                           float* __restrict__ s) {
  int o = blockIdx.x;
  int lane = threadIdx.x & 63, dq = threadIdx.x >> 6;
  int n0 = blockIdx.y * 256 + lane * 4;

  float4 a[32];
#pragma unroll
  for (int b = 0; b < 32; ++b) a[b] = make_float4(0.f, 0.f, 0.f, 0.f);

#pragma unroll 1
  for (int j = 0; j < 4; ++j) {
    int n = n0 + j;
    if (n < 2592) {
      const float4* wp = (const float4*)(W + ((size_t)(o * 2592 + n) * 16 + dq * 4) * 8);
      float4 w0 = wp[0], w1 = wp[1], w2 = wp[2], w3 = wp[3];
      float4 w4 = wp[4], w5 = wp[5], w6 = wp[6], w7 = wp[7];
#pragma unroll
      for (int b = 0; b < 32; ++b) {
        const float* up = u3g + b * 8 * 2592 + n;
        float uu0 = up[0], uu1 = up[2592], uu2 = up[5184], uu3 = up[7776];
        float uu4 = up[10368], uu5 = up[12960], uu6 = up[15552], uu7 = up[18144];
        float cv = HASC ? c3[(size_t)(o * 32 + b) * 2592 + n] : 1.0f;
        float x0 = w0.x * uu0 + w0.y * uu1 + w0.z * uu2 + w0.w * uu3 +
                   w1.x * uu4 + w1.y * uu5 + w1.z * uu6 + w1.w * uu7;
        float x1 = w2.x * uu0 + w2.y * uu1 + w2.z * uu2 + w2.w * uu3 +
                   w3.x * uu4 + w3.y * uu5 + w3.z * uu6 + w3.w * uu7;
        float x2 = w4.x * uu0 + w4.y * uu1 + w4.z * uu2 + w4.w * uu3 +
                   w5.x * uu4 + w5.y * uu5 + w5.z * uu6 + w5.w * uu7;
        float x3 = w6.x * uu0 + w6.y * uu1 + w6.z * uu2 + w6.w * uu3 +
                   w7.x * uu4 + w7.y * uu5 + w7.z * uu6 + w7.w * uu7;
        a[b].x += cv * x0; a[b].y += cv * x1; a[b].z += cv * x2; a[b].w += cv * x3;
      }
    }
  }
  // xor all-reduce over 64 lanes (sum over this wave's n)
#pragma unroll
  for (int m = 1; m < 64; m <<= 1) {
#pragma unroll
    for (int b = 0; b < 32; ++b) {
      a[b].x += __shfl_xor(a[b].x, m);
      a[b].y += __shfl_xor(a[b].y, m);
      a[b].z += __shfl_xor(a[b].z, m);
      a[b].w += __shfl_xor(a[b].w, m);
    }
  }
  // 2 atomics per lane, compile-time (b,ds) with exec-mask selection
#pragma unroll
  for (int b = 0; b < 32; ++b) {
#pragma unroll
    for (int ds = 0; ds < 4; ++ds) {
      float v = (ds == 0) ? a[b].x : (ds == 1) ? a[b].y : (ds == 2) ? a[b].z : a[b].w;
      if (lane == ((b * 4 + ds) & 63))
        atomicAdd(s + (b * 102 + o) * 16 + dq * 4 + ds, v);
    }
  }
}

// ---------------- squash v (dim 16), optional vsum ----------------
__global__ void k_R(const float* __restrict__ s, float scale,
                    float* __restrict__ vout, const float* __restrict__ v0in,
                    float* __restrict__ vsout) {
  int t = blockIdx.x * 256 + threadIdx.x;
  if (t >= 3264) return;
  const float* sp = s + t * 16;
  float r[16];
  float sq = 0.f;
#pragma unroll
  for (int d = 0; d < 16; ++d) {
    r[d] = sp[d] * scale;
    sq += r[d] * r[d];
  }
  float sc = (sq / (1.f + sq)) / sqrtf(sq + 1e-8f);
#pragma unroll
  for (int d = 0; d < 16; ++d) {
    float vv = r[d] * sc;
    vout[t * 16 + d] = vv;
    if (vsout) vsout[t * 16 + d] = v0in[t * 16 + d] + vv;
  }
}

// ---------------- fc chain ----------------
__global__ void k_fc1(const float* __restrict__ v2, const int* __restrict__ tgt,
                      const float* __restrict__ w1, const float* __restrict__ b1,
                      float* __restrict__ h1) {
  int j = blockIdx.x * 128 + threadIdx.x;  // < 512
  int bq = blockIdx.y;                     // 8 groups of 4
#pragma unroll
  for (int bi = 0; bi < 4; ++bi) {
    int b = bq * 4 + bi;
    int tb = tgt[b];
    float acc = b1[j];
    const float* vv = v2 + (b * 102 + tb) * 16;
    const float* wr = w1 + (tb * 16) * 512 + j;
#pragma unroll
    for (int d = 0; d < 16; ++d) acc += vv[d] * wr[d * 512];
    h1[b * 512 + j] = fmaxf(acc, 0.f);
  }
}

__global__ void k_fc2(const float* __restrict__ h1, const float* __restrict__ w2,
                      const float* __restrict__ b2, float* __restrict__ h2T) {
  int j = blockIdx.x * 128 + threadIdx.x;  // < 1024
  int bq = blockIdx.y;                     // 8 groups of 4
  float acc[4];
#pragma unroll
  for (int bi = 0; bi < 4; ++bi) acc[bi] = b2[j];
  for (int k = 0; k < 512; ++k) {
    float wv = w2[k * 1024 + j];
#pragma unroll
    for (int bi = 0; bi < 4; ++bi) acc[bi] += h1[(bq * 4 + bi) * 512 + k] * wv;
  }
  float4 o;
  o.x = fmaxf(acc[0], 0.f); o.y = fmaxf(acc[1], 0.f);
  o.z = fmaxf(acc[2], 0.f); o.w = fmaxf(acc[3], 0.f);
  *(float4*)(h2T + j * 32 + bq * 4) = o;
}

__global__ void k_fc3(const float* __restrict__ h2T, const float* __restrict__ w3,
                      const float* __restrict__ b3, float* __restrict__ out) {
  int j = blockIdx.x * 128 + threadIdx.x;  // < 37632
  int bq = blockIdx.y;                     // 4 groups of 8
  float acc[8];
  float bv = b3[j];
#pragma unroll
  for (int i = 0; i < 8; ++i) acc[i] = bv;
  for (int k = 0; k < 1024; ++k) {
    float wv = w3[(size_t)k * 37632 + j];
    const float4* hp = (const float4*)(h2T + k * 32 + bq * 8);
    float4 ha = hp[0], hb = hp[1];
    acc[0] += ha.x * wv; acc[1] += ha.y * wv; acc[2] += ha.z * wv; acc[3] += ha.w * wv;
    acc[4] += hb.x * wv; acc[5] += hb.y * wv; acc[6] += hb.z * wv; acc[7] += hb.w * wv;
  }
#pragma unroll
  for (int i = 0; i < 8; ++i) {
    float sg = 1.0f / (1.0f + __expf(-acc[i]));
    out[52224 + (size_t)(bq * 8 + i) * 37632 + j] = sg;
  }
}

// ---------------- host ----------------
extern "C" void kernel_launch(void* const* d_in, const int* in_sizes, int n_in,
                              void* d_out, int out_size, void* d_ws, size_t ws_size,
                              hipStream_t stream) {
  const float* x       = (const float*)d_in[0];
  const int*   targets = (const int*)d_in[1];
  const float* conv1_w = (const float*)d_in[2];
  const float* conv1_b = (const float*)d_in[3];
  const float* pc_w    = (const float*)d_in[4];
  const float* pc_b    = (const float*)d_in[5];
  const float* W       = (const float*)d_in[6];
  const float* fc1_w   = (const float*)d_in[7];
  const float* fc1_b   = (const float*)d_in[8];
  const float* fc2_w   = (const float*)d_in[9];
  const float* fc2_b   = (const float*)d_in[10];
  const float* fc3_w   = (const float*)d_in[11];
  const float* fc3_b   = (const float*)d_in[12];
  float* out = (float*)d_out;
  float* ws = (float*)d_ws;

  float* FEAT = ws + OFF_FEAT;
  float* C1WT = ws + OFF_C1WT;
  float* PCWT = ws + OFF_PCWT;
  float* PCP  = ws + OFF_PCP;
  float* PC2  = ws + OFF_PC2;
  float* U2   = ws + OFF_U2;
  float* U3   = ws + OFF_U3;
  float* C3   = ws + OFF_C3;
  float* S    = ws + OFF_S;
  float* V0   = ws + OFF_V0;
  float* V1   = ws + OFF_V1;
  float* VS   = ws + OFF_VS;
  float* H1   = ws + OFF_H1;
  float* H2T  = ws + OFF_H2T;

  // weight transposes -> [k][co]
  k_wtrans<<<dim3(6, 4), 256, 0, stream>>>(conv1_w, C1WT, 256, 363);
  k_wtrans<<<dim3(324, 4), 256, 0, stream>>>(pc_w, PCWT, 256, 20736);

  // conv1 + relu
  k_conv1<0><<<dim3(34 * 32), 256, 0, stream>>>(x, C1WT, conv1_b, FEAT);
  k_conv1<3><<<dim3(34 * 32), 256, 0, stream>>>(x, C1WT, conv1_b, FEAT);

  // primary caps conv (partials over 8 ci-chunks) + reduce + bias + squash
  k_pc<<<dim3(1152), 256, 0, stream>>>(FEAT, PCWT, PCP);
  k_pcreduce<<<dim3(2592), 256, 0, stream>>>(PCP, pc_b, PC2);
  k_squash<<<dim3(324), 256, 0, stream>>>(PC2, U2, U3);

  // ---- routing ----
  // it0: c uniform 1/102 (fold into squash scale)
  hipMemsetAsync(S, 0, 52224 * sizeof(float), stream);
  k_B<false><<<dim3(102, 11), 256, 0, stream>>>(W, U3, nullptr, S);
  k_R<<<dim3(13), 256, 0, stream>>>(S, 1.0f / 102.0f, V0, nullptr, nullptr);

  // it1: c = softmax(xhat . v0)
  k_A<<<dim3(864), 128, 0, stream>>>(W, U2, V0, C3);
  hipMemsetAsync(S, 0, 52224 * sizeof(float), stream);
  k_B<true><<<dim3(102, 11), 256, 0, stream>>>(W, U3, C3, S);
  k_R<<<dim3(13), 256, 0, stream>>>(S, 1.0f, V1, V0, VS);  // VS = v0 + v1

  // it2: c = softmax(xhat . (v0+v1)); final v -> d_out[0:52224)
  k_A<<<dim3(864), 128, 0, stream>>>(W, U2, VS, C3);
  hipMemsetAsync(S, 0, 52224 * sizeof(float), stream);
  k_B<true><<<dim3(102, 11), 256, 0, stream>>>(W, U3, C3, S);
  k_R<<<dim3(13), 256, 0, stream>>>(S, 1.0f, out, nullptr, nullptr);

  // ---- reconstruction ----
  k_fc1<<<dim3(4, 8), 128, 0, stream>>>(out, targets, fc1_w, fc1_b, H1);
  k_fc2<<<dim3(8, 8), 128, 0, stream>>>(H1, fc2_w, fc2_b, H2T);
  k_fc3<<<dim3(294, 4), 128, 0, stream>>>(H2T, fc3_w, fc3_b, out);
}

// Round 2
// 2031.533 us; speedup vs baseline: 1.2305x; 1.2305x over previous
//
#include <hip/hip_runtime.h>
#include <math.h>

// ---------------- sizes ----------------
#define B32   32
#define OCLS  102
#define NCAPS 2592
#define DIN   8
#define DOUT  16

// ws offsets (in floats); all multiples of 4 -> 16B aligned
#define OFF_FEAT   0u               // 32*256*34*36 = 10,027,008
#define OFF_C1WT   10027008u        // 363*256      =     92,928
#define OFF_PCWT   10119936u        // bf16 B-pack: 256*256*104 ushort = 13.6MB (< slot)
#define OFF_PCP    15428352u        // 8*32*81*256  =  5,308,416
#define OFF_PC2    20736768u        // 32*81*256    =    663,552
#define OFF_U2     21400320u        // 32*2592*8
#define OFF_U3     22063872u        // 32*8*2592
#define OFF_C3     22727424u        // 102*32*2592  =  8,460,288
#define OFF_S      31187712u        // 32*102*16    =     52,224
#define OFF_V0     31239936u
#define OFF_V1     31292160u
#define OFF_VS     31344384u
#define OFF_H1     31396608u        // 32*512
#define OFF_H2T    31412992u        // 1024*32

typedef __attribute__((ext_vector_type(8))) short short8;
typedef __attribute__((ext_vector_type(4))) float f32x4;

__device__ __forceinline__ unsigned short f2b(float f) {
  union { float f; unsigned u; } v; v.f = f;
  unsigned r = v.u + 0x7fffu + ((v.u >> 16) & 1u);
  return (unsigned short)(r >> 16);
}

// ---------------- weight transpose [CO][K] -> [K][CO] (conv1 only) ----------------
__global__ void k_wtrans(const float* __restrict__ in, float* __restrict__ out,
                         int CO, int K) {
  __shared__ float t[64][65];
  int kb = blockIdx.x * 64, cb = blockIdx.y * 64;
  int tx = threadIdx.x & 63, ty = threadIdx.x >> 6;
  for (int r = ty; r < 64; r += 4) {
    int co = cb + r, k = kb + tx;
    t[r][tx] = (k < K) ? in[(size_t)co * K + k] : 0.f;
  }
  __syncthreads();
  for (int r = ty; r < 64; r += 4) {
    int k = kb + r, co = cb + tx;
    if (k < K) out[(size_t)k * CO + co] = t[tx][r];
  }
}

// ---------------- pc_w repack -> bf16 [ci][co][104] (taps 0..80 real, 81..103 zero) ----
__global__ void k_mkB(const float* __restrict__ pc_w, unsigned short* __restrict__ PCWB) {
  int co = blockIdx.x;
  for (int e = threadIdx.x; e < 20736; e += 256) {
    int ci = e / 81, tap = e - ci * 81;
    PCWB[(size_t)ci * 26624 + co * 104 + tap] = f2b(pc_w[(size_t)co * 20736 + e]);
  }
  int ci = threadIdx.x;  // 0..255
  for (int tap = 81; tap < 104; ++tap)
    PCWB[(size_t)ci * 26624 + co * 104 + tap] = 0;
}

// ---------------- conv1 11x11 s3 + bias + relu ----------------
template <int OFF>
__global__ __launch_bounds__(256) void k_conv1(const float* __restrict__ x,
                                               const float* __restrict__ c1wT,
                                               const float* __restrict__ bias,
                                               float* __restrict__ feat) {
  int bx = blockIdx.x;
  int ho = bx % 34, b = bx / 34;
  int co = threadIdx.x;
  const int wobase = (OFF == 0) ? 0 : 17;
  const int a0 = (OFF == 0) ? 0 : 48;

  float bv = bias[co];
  float acc[17];
#pragma unroll
  for (int w = 0; w < 17; ++w) acc[w] = bv;

#pragma unroll 1
  for (int ci = 0; ci < 3; ++ci) {
#pragma unroll 1
    for (int kh = 0; kh < 11; ++kh) {
      int h = ho * 3 + kh;
      const float4* xr = (const float4*)(x + ((b * 3 + ci) * 112 + h) * 112 + a0);
      float w_[11];
#pragma unroll
      for (int kw = 0; kw < 11; ++kw)
        w_[kw] = c1wT[((ci * 11 + kh) * 11 + kw) * 256 + co];
      float rr[64];
#pragma unroll
      for (int q = 0; q < 16; ++q) {
        float4 v = xr[q];
        rr[4 * q] = v.x; rr[4 * q + 1] = v.y; rr[4 * q + 2] = v.z; rr[4 * q + 3] = v.w;
      }
#pragma unroll
      for (int w = 0; w < 17; ++w)
#pragma unroll
        for (int kw = 0; kw < 11; ++kw)
          acc[w] += w_[kw] * rr[3 * w + kw + OFF];
    }
  }
  __shared__ float ot[256 * 17];
#pragma unroll
  for (int w = 0; w < 17; ++w) ot[co * 17 + w] = fmaxf(acc[w], 0.f);
  __syncthreads();
  for (int it = 0; it < 17; ++it) {
    int idx = it * 256 + threadIdx.x;
    int c2 = idx / 17, w2 = idx - c2 * 17;
    feat[((b * 256 + c2) * 34 + ho) * 36 + wobase + w2] = ot[idx];
  }
}

// ---------------- primary caps conv: bf16 MFMA implicit-im2col GEMM ----------------
// M=2592 (b*81+p), N=256 (co), K per ci = 81 taps (pad 96 -> 3 K32-steps).
// grid (41 mb, 8 kc); block 256 thr = 4 waves, each wave owns 64 co.
// LDS: A-tile [64][104] bf16, B-tile [256][104] bf16 (pad cols zeroed once).
__global__ __launch_bounds__(256) void k_pc2(const float* __restrict__ feat,
                                             const unsigned short* __restrict__ PCWB,
                                             float* __restrict__ pcp) {
  __shared__ unsigned short sh[64 * 104 + 256 * 104];
  unsigned short* lA = sh;
  unsigned short* lB = sh + 64 * 104;

  int mb = blockIdx.x, kc = blockIdx.y;
  int t = threadIdx.x;
  int lane = t & 63, wv = t >> 6;
  int l15 = lane & 15, lh = lane >> 4;

  // zero-init whole LDS once (pad cols + tail-M rows stay zero)
  {
    uint4 zz = make_uint4(0, 0, 0, 0);
    uint4* z = (uint4*)sh;
    for (int i = t; i < (64 * 104 + 256 * 104) / 8; i += 256) z[i] = zz;
  }
  __syncthreads();

  f32x4 acc[4][4];
#pragma unroll
  for (int mf = 0; mf < 4; ++mf)
#pragma unroll
    for (int nf = 0; nf < 4; ++nf) acc[mf][nf] = (f32x4){0.f, 0.f, 0.f, 0.f};

  const unsigned short* arow = lA + l15 * 104 + lh * 8;
  const unsigned short* brow = lB + (wv * 64 + l15) * 104 + lh * 8;

#pragma unroll 1
  for (int cil = 0; cil < 32; ++cil) {
    int ci = kc * 32 + cil;

    // stage B: flat copy 3328 x 16B, coalesced
    {
      const unsigned short* Bsrc = PCWB + (size_t)ci * 26624;
#pragma unroll
      for (int i = 0; i < 13; ++i) {
        int f = i * 256 + t;
        ((uint4*)lB)[f] = *(const uint4*)(Bsrc + (size_t)f * 8);
      }
    }
    // stage A: 576 tasks (m,kh), 9 floats each, cvt bf16
    for (int task = t; task < 576; task += 256) {
      int m = task / 9, kh = task - m * 9;
      int gm = mb * 64 + m;
      if (gm < 2592) {
        int b = gm / 81, p = gm - b * 81;
        int ho = p / 9, wo = p - ho * 9;
        const float* src = feat + (size_t)((b * 256 + ci) * 34 + ho * 3 + kh) * 36 + wo * 3;
        unsigned short* dst = lA + m * 104 + kh * 9;
#pragma unroll
        for (int j = 0; j < 9; ++j) dst[j] = f2b(src[j]);
      }
    }
    __syncthreads();

#pragma unroll
    for (int s = 0; s < 3; ++s) {
      short8 a0 = *(const short8*)(arow + s * 32);
      short8 a1 = *(const short8*)(arow + 16 * 104 + s * 32);
      short8 a2 = *(const short8*)(arow + 32 * 104 + s * 32);
      short8 a3 = *(const short8*)(arow + 48 * 104 + s * 32);
      short8 b0 = *(const short8*)(brow + s * 32);
      short8 b1 = *(const short8*)(brow + 16 * 104 + s * 32);
      short8 b2 = *(const short8*)(brow + 32 * 104 + s * 32);
      short8 b3 = *(const short8*)(brow + 48 * 104 + s * 32);
      acc[0][0] = __builtin_amdgcn_mfma_f32_16x16x32_bf16(a0, b0, acc[0][0], 0, 0, 0);
      acc[0][1] = __builtin_amdgcn_mfma_f32_16x16x32_bf16(a0, b1, acc[0][1], 0, 0, 0);
      acc[0][2] = __builtin_amdgcn_mfma_f32_16x16x32_bf16(a0, b2, acc[0][2], 0, 0, 0);
      acc[0][3] = __builtin_amdgcn_mfma_f32_16x16x32_bf16(a0, b3, acc[0][3], 0, 0, 0);
      acc[1][0] = __builtin_amdgcn_mfma_f32_16x16x32_bf16(a1, b0, acc[1][0], 0, 0, 0);
      acc[1][1] = __builtin_amdgcn_mfma_f32_16x16x32_bf16(a1, b1, acc[1][1], 0, 0, 0);
      acc[1][2] = __builtin_amdgcn_mfma_f32_16x16x32_bf16(a1, b2, acc[1][2], 0, 0, 0);
      acc[1][3] = __builtin_amdgcn_mfma_f32_16x16x32_bf16(a1, b3, acc[1][3], 0, 0, 0);
      acc[2][0] = __builtin_amdgcn_mfma_f32_16x16x32_bf16(a2, b0, acc[2][0], 0, 0, 0);
      acc[2][1] = __builtin_amdgcn_mfma_f32_16x16x32_bf16(a2, b1, acc[2][1], 0, 0, 0);
      acc[2][2] = __builtin_amdgcn_mfma_f32_16x16x32_bf16(a2, b2, acc[2][2], 0, 0, 0);
      acc[2][3] = __builtin_amdgcn_mfma_f32_16x16x32_bf16(a2, b3, acc[2][3], 0, 0, 0);
      acc[3][0] = __builtin_amdgcn_mfma_f32_16x16x32_bf16(a3, b0, acc[3][0], 0, 0, 0);
      acc[3][1] = __builtin_amdgcn_mfma_f32_16x16x32_bf16(a3, b1, acc[3][1], 0, 0, 0);
      acc[3][2] = __builtin_amdgcn_mfma_f32_16x16x32_bf16(a3, b2, acc[3][2], 0, 0, 0);
      acc[3][3] = __builtin_amdgcn_mfma_f32_16x16x32_bf16(a3, b3, acc[3][3], 0, 0, 0);
    }
    __syncthreads();
  }

  // store: C row m = (lane>>4)*4 + reg, col n = lane&15  [measured m89/m91 layout]
#pragma unroll
  for (int mf = 0; mf < 4; ++mf) {
    int gm = mb * 64 + mf * 16 + lh * 4;  // gm % 4 == 0, 2592 % 4 == 0 -> all-or-none
    if (gm < 2592) {
      float* dst = pcp + (size_t)kc * 663552 + (size_t)gm * 256 + wv * 64 + l15;
#pragma unroll
      for (int nf = 0; nf < 4; ++nf)
#pragma unroll
        for (int r = 0; r < 4; ++r)
          dst[(size_t)r * 256 + nf * 16] = acc[mf][nf][r];
    }
  }
}

// sum 8 ci-chunk partials + bias
__global__ void k_pcreduce(const float* __restrict__ pcp,
                           const float* __restrict__ pcb,
                           float* __restrict__ pc2) {
  int i = blockIdx.x * 256 + threadIdx.x;  // < 663552
  float s = pcb[i & 255];
#pragma unroll
  for (int c = 0; c < 8; ++c) s += pcp[c * 663552 + i];
  pc2[i] = s;
}

// squash u (dim 8); write u2[b][n][i] and u3[b][i][n]
__global__ void k_squash(const float* __restrict__ pc2,
                         float* __restrict__ u2, float* __restrict__ u3) {
  int t = blockIdx.x * 256 + threadIdx.x;  // < 82944
  int b = t / 2592, n = t - b * 2592;
  float v[8];
  float sq = 0.f;
#pragma unroll
  for (int i = 0; i < 8; ++i) {
    int f = n * 8 + i;
    int co = f / 81, p = f - co * 81;
    v[i] = pc2[(b * 81 + p) * 256 + co];
    sq += v[i] * v[i];
  }
  float sc = (sq / (1.f + sq)) / sqrtf(sq + 1e-8f);
#pragma unroll
  for (int i = 0; i < 8; ++i) {
    float uv = v[i] * sc;
    u2[t * 8 + i] = uv;
    u3[(b * 8 + i) * 2592 + n] = uv;
  }
}

// ---------------- routing kernel A: logits + softmax -> c3[o][b][n] ----------------
__global__ __launch_bounds__(128) void k_A(const float* __restrict__ W,
                                           const float* __restrict__ u2,
                                           const float* __restrict__ vsum,
                                           float* __restrict__ c3) {
  __shared__ float red[102 * 33];
  __shared__ float r2[4 * 33];
  __shared__ float ctile[102 * 33 * 3];
  int o = threadIdx.x;
  int nb = blockIdx.x;  // 864

  for (int nt = 0; nt < 3; ++nt) {
    int n = nb * 3 + nt;
    if (o < 102) {
      float4 wf[32];
      const float4* wp = (const float4*)(W + (size_t)(o * 2592 + n) * 128);
#pragma unroll
      for (int q = 0; q < 32; ++q) wf[q] = wp[q];
#pragma unroll 1
      for (int b = 0; b < 32; ++b) {
        float vr[16];
        {
          const float4* vp = (const float4*)(vsum + (b * 102 + o) * 16);
          float4 q0 = vp[0], q1 = vp[1], q2 = vp[2], q3 = vp[3];
          vr[0] = q0.x; vr[1] = q0.y; vr[2] = q0.z; vr[3] = q0.w;
          vr[4] = q1.x; vr[5] = q1.y; vr[6] = q1.z; vr[7] = q1.w;
          vr[8] = q2.x; vr[9] = q2.y; vr[10] = q2.z; vr[11] = q2.w;
          vr[12] = q3.x; vr[13] = q3.y; vr[14] = q3.z; vr[15] = q3.w;
        }
        float tt[8] = {0, 0, 0, 0, 0, 0, 0, 0};
#pragma unroll
        for (int d = 0; d < 16; ++d) {
          float vd = vr[d];
          float4 wa = wf[2 * d], wb = wf[2 * d + 1];
          tt[0] += wa.x * vd; tt[1] += wa.y * vd; tt[2] += wa.z * vd; tt[3] += wa.w * vd;
          tt[4] += wb.x * vd; tt[5] += wb.y * vd; tt[6] += wb.z * vd; tt[7] += wb.w * vd;
        }
        const float4* up = (const float4*)(u2 + (size_t)(b * 2592 + n) * 8);
        float4 ua = up[0], ub = up[1];
        float dlt = tt[0] * ua.x + tt[1] * ua.y + tt[2] * ua.z + tt[3] * ua.w +
                    tt[4] * ub.x + tt[5] * ub.y + tt[6] * ub.z + tt[7] * ub.w;
        red[o * 33 + b] = __expf(dlt);
      }
    }
    __syncthreads();
    {
      int bb = threadIdx.x & 31, g = threadIdx.x >> 5;
      float ps = 0.f;
      int oend = (g * 26 + 26 < 102) ? g * 26 + 26 : 102;
      for (int oo = g * 26; oo < oend; ++oo) ps += red[oo * 33 + bb];
      r2[g * 33 + bb] = ps;
    }
    __syncthreads();
    if (threadIdx.x < 32) {
      int bb = threadIdx.x;
      r2[bb] = 1.0f / (r2[bb] + r2[33 + bb] + r2[66 + bb] + r2[99 + bb]);
    }
    __syncthreads();
    if (o < 102) {
#pragma unroll 1
      for (int b = 0; b < 32; ++b)
        ctile[(o * 33 + b) * 3 + nt] = red[o * 33 + b] * r2[b];
    }
    __syncthreads();
  }
  for (int it = 0; it < 26; ++it) {
    int idx = it * 128 + threadIdx.x;
    if (idx < 3264) {
      int oo = idx >> 5, bb = idx & 31;
      float* dst = c3 + (size_t)(oo * 32 + bb) * 2592 + nb * 3;
      dst[0] = ctile[(oo * 33 + bb) * 3 + 0];
      dst[1] = ctile[(oo * 33 + bb) * 3 + 1];
      dst[2] = ctile[(oo * 33 + bb) * 3 + 2];
    }
  }
}

// ---------------- routing kernel B: s[b,o,d] += sum_n c * xhat ----------------
template <bool HASC>
__global__ __launch_bounds__(256) void k_B(const float* __restrict__ W,
                                           const float* __restrict__ u3g,
                                           const float* __restrict__ c3,
                                           float* __restrict__ s) {
  int o = blockIdx.x;
  int lane = threadIdx.x & 63, dq = threadIdx.x >> 6;
  int n0 = blockIdx.y * 256 + lane * 4;

  float4 a[32];
#pragma unroll
  for (int b = 0; b < 32; ++b) a[b] = make_float4(0.f, 0.f, 0.f, 0.f);

#pragma unroll 1
  for (int j = 0; j < 4; ++j) {
    int n = n0 + j;
    if (n < 2592) {
      const float4* wp = (const float4*)(W + ((size_t)(o * 2592 + n) * 16 + dq * 4) * 8);
      float4 w0 = wp[0], w1 = wp[1], w2 = wp[2], w3 = wp[3];
      float4 w4 = wp[4], w5 = wp[5], w6 = wp[6], w7 = wp[7];
#pragma unroll
      for (int b = 0; b < 32; ++b) {
        const float* up = u3g + b * 8 * 2592 + n;
        float uu0 = up[0], uu1 = up[2592], uu2 = up[5184], uu3 = up[7776];
        float uu4 = up[10368], uu5 = up[12960], uu6 = up[15552], uu7 = up[18144];
        float cv = HASC ? c3[(size_t)(o * 32 + b) * 2592 + n] : 1.0f;
        float x0 = w0.x * uu0 + w0.y * uu1 + w0.z * uu2 + w0.w * uu3 +
                   w1.x * uu4 + w1.y * uu5 + w1.z * uu6 + w1.w * uu7;
        float x1 = w2.x * uu0 + w2.y * uu1 + w2.z * uu2 + w2.w * uu3 +
                   w3.x * uu4 + w3.y * uu5 + w3.z * uu6 + w3.w * uu7;
        float x2 = w4.x * uu0 + w4.y * uu1 + w4.z * uu2 + w4.w * uu3 +
                   w5.x * uu4 + w5.y * uu5 + w5.z * uu6 + w5.w * uu7;
        float x3 = w6.x * uu0 + w6.y * uu1 + w6.z * uu2 + w6.w * uu3 +
                   w7.x * uu4 + w7.y * uu5 + w7.z * uu6 + w7.w * uu7;
        a[b].x += cv * x0; a[b].y += cv * x1; a[b].z += cv * x2; a[b].w += cv * x3;
      }
    }
  }
#pragma unroll
  for (int m = 1; m < 64; m <<= 1) {
#pragma unroll
    for (int b = 0; b < 32; ++b) {
      a[b].x += __shfl_xor(a[b].x, m);
      a[b].y += __shfl_xor(a[b].y, m);
      a[b].z += __shfl_xor(a[b].z, m);
      a[b].w += __shfl_xor(a[b].w, m);
    }
  }
#pragma unroll
  for (int b = 0; b < 32; ++b) {
#pragma unroll
    for (int ds = 0; ds < 4; ++ds) {
      float v = (ds == 0) ? a[b].x : (ds == 1) ? a[b].y : (ds == 2) ? a[b].z : a[b].w;
      if (lane == ((b * 4 + ds) & 63))
        atomicAdd(s + (b * 102 + o) * 16 + dq * 4 + ds, v);
    }
  }
}

// ---------------- squash v (dim 16), optional vsum ----------------
__global__ void k_R(const float* __restrict__ s, float scale,
                    float* __restrict__ vout, const float* __restrict__ v0in,
                    float* __restrict__ vsout) {
  int t = blockIdx.x * 256 + threadIdx.x;
  if (t >= 3264) return;
  const float* sp = s + t * 16;
  float r[16];
  float sq = 0.f;
#pragma unroll
  for (int d = 0; d < 16; ++d) {
    r[d] = sp[d] * scale;
    sq += r[d] * r[d];
  }
  float sc = (sq / (1.f + sq)) / sqrtf(sq + 1e-8f);
#pragma unroll
  for (int d = 0; d < 16; ++d) {
    float vv = r[d] * sc;
    vout[t * 16 + d] = vv;
    if (vsout) vsout[t * 16 + d] = v0in[t * 16 + d] + vv;
  }
}

// ---------------- fc chain ----------------
__global__ void k_fc1(const float* __restrict__ v2, const int* __restrict__ tgt,
                      const float* __restrict__ w1, const float* __restrict__ b1,
                      float* __restrict__ h1) {
  int j = blockIdx.x * 128 + threadIdx.x;  // < 512
  int bq = blockIdx.y;                     // 8 groups of 4
#pragma unroll
  for (int bi = 0; bi < 4; ++bi) {
    int b = bq * 4 + bi;
    int tb = tgt[b];
    float acc = b1[j];
    const float* vv = v2 + (b * 102 + tb) * 16;
    const float* wr = w1 + (tb * 16) * 512 + j;
#pragma unroll
    for (int d = 0; d < 16; ++d) acc += vv[d] * wr[d * 512];
    h1[b * 512 + j] = fmaxf(acc, 0.f);
  }
}

__global__ void k_fc2(const float* __restrict__ h1, const float* __restrict__ w2,
                      const float* __restrict__ b2, float* __restrict__ h2T) {
  int j = blockIdx.x * 128 + threadIdx.x;  // < 1024
  int bq = blockIdx.y;                     // 8 groups of 4
  float acc[4];
#pragma unroll
  for (int bi = 0; bi < 4; ++bi) acc[bi] = b2[j];
  for (int k = 0; k < 512; ++k) {
    float wv = w2[k * 1024 + j];
#pragma unroll
    for (int bi = 0; bi < 4; ++bi) acc[bi] += h1[(bq * 4 + bi) * 512 + k] * wv;
  }
  float4 o;
  o.x = fmaxf(acc[0], 0.f); o.y = fmaxf(acc[1], 0.f);
  o.z = fmaxf(acc[2], 0.f); o.w = fmaxf(acc[3], 0.f);
  *(float4*)(h2T + j * 32 + bq * 4) = o;
}

__global__ void k_fc3(const float* __restrict__ h2T, const float* __restrict__ w3,
                      const float* __restrict__ b3, float* __restrict__ out) {
  int j = blockIdx.x * 128 + threadIdx.x;  // < 37632
  int bq = blockIdx.y;                     // 4 groups of 8
  float acc[8];
  float bv = b3[j];
#pragma unroll
  for (int i = 0; i < 8; ++i) acc[i] = bv;
  for (int k = 0; k < 1024; ++k) {
    float wv = w3[(size_t)k * 37632 + j];
    const float4* hp = (const float4*)(h2T + k * 32 + bq * 8);
    float4 ha = hp[0], hb = hp[1];
    acc[0] += ha.x * wv; acc[1] += ha.y * wv; acc[2] += ha.z * wv; acc[3] += ha.w * wv;
    acc[4] += hb.x * wv; acc[5] += hb.y * wv; acc[6] += hb.z * wv; acc[7] += hb.w * wv;
  }
#pragma unroll
  for (int i = 0; i < 8; ++i) {
    float sg = 1.0f / (1.0f + __expf(-acc[i]));
    out[52224 + (size_t)(bq * 8 + i) * 37632 + j] = sg;
  }
}

// ---------------- host ----------------
extern "C" void kernel_launch(void* const* d_in, const int* in_sizes, int n_in,
                              void* d_out, int out_size, void* d_ws, size_t ws_size,
                              hipStream_t stream) {
  const float* x       = (const float*)d_in[0];
  const int*   targets = (const int*)d_in[1];
  const float* conv1_w = (const float*)d_in[2];
  const float* conv1_b = (const float*)d_in[3];
  const float* pc_w    = (const float*)d_in[4];
  const float* pc_b    = (const float*)d_in[5];
  const float* W       = (const float*)d_in[6];
  const float* fc1_w   = (const float*)d_in[7];
  const float* fc1_b   = (const float*)d_in[8];
  const float* fc2_w   = (const float*)d_in[9];
  const float* fc2_b   = (const float*)d_in[10];
  const float* fc3_w   = (const float*)d_in[11];
  const float* fc3_b   = (const float*)d_in[12];
  float* out = (float*)d_out;
  float* ws = (float*)d_ws;

  float* FEAT = ws + OFF_FEAT;
  float* C1WT = ws + OFF_C1WT;
  unsigned short* PCWB = (unsigned short*)(ws + OFF_PCWT);
  float* PCP  = ws + OFF_PCP;
  float* PC2  = ws + OFF_PC2;
  float* U2   = ws + OFF_U2;
  float* U3   = ws + OFF_U3;
  float* C3   = ws + OFF_C3;
  float* S    = ws + OFF_S;
  float* V0   = ws + OFF_V0;
  float* V1   = ws + OFF_V1;
  float* VS   = ws + OFF_VS;
  float* H1   = ws + OFF_H1;
  float* H2T  = ws + OFF_H2T;

  // weight prep
  k_wtrans<<<dim3(6, 4), 256, 0, stream>>>(conv1_w, C1WT, 256, 363);
  k_mkB<<<dim3(256), 256, 0, stream>>>(pc_w, PCWB);

  // conv1 + relu
  k_conv1<0><<<dim3(34 * 32), 256, 0, stream>>>(x, C1WT, conv1_b, FEAT);
  k_conv1<3><<<dim3(34 * 32), 256, 0, stream>>>(x, C1WT, conv1_b, FEAT);

  // primary caps conv via bf16 MFMA (8 ci-chunks) + reduce + bias + squash
  k_pc2<<<dim3(41, 8), 256, 0, stream>>>(FEAT, PCWB, PCP);
  k_pcreduce<<<dim3(2592), 256, 0, stream>>>(PCP, pc_b, PC2);
  k_squash<<<dim3(324), 256, 0, stream>>>(PC2, U2, U3);

  // ---- routing ----
  hipMemsetAsync(S, 0, 52224 * sizeof(float), stream);
  k_B<false><<<dim3(102, 11), 256, 0, stream>>>(W, U3, nullptr, S);
  k_R<<<dim3(13), 256, 0, stream>>>(S, 1.0f / 102.0f, V0, nullptr, nullptr);

  k_A<<<dim3(864), 128, 0, stream>>>(W, U2, V0, C3);
  hipMemsetAsync(S, 0, 52224 * sizeof(float), stream);
  k_B<true><<<dim3(102, 11), 256, 0, stream>>>(W, U3, C3, S);
  k_R<<<dim3(13), 256, 0, stream>>>(S, 1.0f, V1, V0, VS);  // VS = v0 + v1

  k_A<<<dim3(864), 128, 0, stream>>>(W, U2, VS, C3);
  hipMemsetAsync(S, 0, 52224 * sizeof(float), stream);
  k_B<true><<<dim3(102, 11), 256, 0, stream>>>(W, U3, C3, S);
  k_R<<<dim3(13), 256, 0, stream>>>(S, 1.0f, out, nullptr, nullptr);

  // ---- reconstruction ----
  k_fc1<<<dim3(4, 8), 128, 0, stream>>>(out, targets, fc1_w, fc1_b, H1);
  k_fc2<<<dim3(8, 8), 128, 0, stream>>>(H1, fc2_w, fc2_b, H2T);
  k_fc3<<<dim3(294, 4), 128, 0, stream>>>(H2T, fc3_w, fc3_b, out);
}

// Round 3
// 978.897 us; speedup vs baseline: 2.5538x; 2.0753x over previous
//
#include <hip/hip_runtime.h>
#include <hip/hip_fp16.h>
#include <math.h>

// ---------------- sizes ----------------
#define B32   32
#define OCLS  102
#define NCAPS 2592
#define DIN   8
#define DOUT  16

// ws offsets (in floats); all multiples of 4 -> 16B aligned
// Wb (bf16 pack of W, 33,867,776 ushorts = 16,933,888 float-slots) overlays
// [0 .. 16933888): FEAT + C1WT + PCWB + low PCP -- all dead after k_squash;
// k_mkWb runs after k_squash.
#define OFF_FEAT   0u               // 32*256*34*36 = 10,027,008
#define OFF_C1WT   10027008u        // 363*256      =     92,928
#define OFF_PCWT   10119936u        // bf16 B-pack: 256*256*104 ushort
#define OFF_PCP    15428352u        // 8*32*81*256  =  5,308,416
#define OFF_PC2    20736768u        // 32*81*256    =    663,552
#define OFF_U2     21400320u        // 32*2592*8
#define OFF_CT     22727424u        // fp16 c[o][n][b]: 8,460,288 halfs = 4.23M floats
#define OFF_S      31187712u        // 32*102*16    =     52,224
#define OFF_V0     31239936u
#define OFF_V1     31292160u
#define OFF_VS     31344384u
#define OFF_H1     31396608u        // 32*512
#define OFF_H2T    31412992u        // 1024*32

typedef __attribute__((ext_vector_type(8))) short short8;
typedef __attribute__((ext_vector_type(4))) float f32x4;

__device__ __forceinline__ unsigned short f2b(float f) {
  union { float f; unsigned u; } v; v.f = f;
  unsigned r = v.u + 0x7fffu + ((v.u >> 16) & 1u);
  return (unsigned short)(r >> 16);
}

// ---------------- weight transpose [CO][K] -> [K][CO] (conv1 only) ----------------
__global__ void k_wtrans(const float* __restrict__ in, float* __restrict__ out,
                         int CO, int K) {
  __shared__ float t[64][65];
  int kb = blockIdx.x * 64, cb = blockIdx.y * 64;
  int tx = threadIdx.x & 63, ty = threadIdx.x >> 6;
  for (int r = ty; r < 64; r += 4) {
    int co = cb + r, k = kb + tx;
    t[r][tx] = (k < K) ? in[(size_t)co * K + k] : 0.f;
  }
  __syncthreads();
  for (int r = ty; r < 64; r += 4) {
    int k = kb + r, co = cb + tx;
    if (k < K) out[(size_t)k * CO + co] = t[tx][r];
  }
}

// ---------------- pc_w repack -> bf16 [ci][co][104] ----------------
__global__ void k_mkB(const float* __restrict__ pc_w, unsigned short* __restrict__ PCWB) {
  int co = blockIdx.x;
  for (int e = threadIdx.x; e < 20736; e += 256) {
    int ci = e / 81, tap = e - ci * 81;
    PCWB[(size_t)ci * 26624 + co * 104 + tap] = f2b(pc_w[(size_t)co * 20736 + e]);
  }
  int ci = threadIdx.x;  // 0..255
  for (int tap = 81; tap < 104; ++tap)
    PCWB[(size_t)ci * 26624 + co * 104 + tap] = 0;
}

// ---------------- routing W -> bf16 Wb[o][n][d][i], same layout ----------------
__global__ void k_mkWb(const float* __restrict__ W, unsigned short* __restrict__ Wb) {
  size_t i = ((size_t)blockIdx.x * 256 + threadIdx.x) * 8;  // 4,233,472 tasks
  const float4* p = (const float4*)(W + i);
  float4 a = p[0], b = p[1];
  unsigned u0 = (unsigned)f2b(a.x) | ((unsigned)f2b(a.y) << 16);
  unsigned u1 = (unsigned)f2b(a.z) | ((unsigned)f2b(a.w) << 16);
  unsigned u2 = (unsigned)f2b(b.x) | ((unsigned)f2b(b.y) << 16);
  unsigned u3 = (unsigned)f2b(b.z) | ((unsigned)f2b(b.w) << 16);
  *(uint4*)(Wb + i) = make_uint4(u0, u1, u2, u3);
}

// ---------------- conv1 11x11 s3 + bias + relu ----------------
template <int OFF>
__global__ __launch_bounds__(256) void k_conv1(const float* __restrict__ x,
                                               const float* __restrict__ c1wT,
                                               const float* __restrict__ bias,
                                               float* __restrict__ feat) {
  int bx = blockIdx.x;
  int ho = bx % 34, b = bx / 34;
  int co = threadIdx.x;
  const int wobase = (OFF == 0) ? 0 : 17;
  const int a0 = (OFF == 0) ? 0 : 48;

  float bv = bias[co];
  float acc[17];
#pragma unroll
  for (int w = 0; w < 17; ++w) acc[w] = bv;

#pragma unroll 1
  for (int ci = 0; ci < 3; ++ci) {
#pragma unroll 1
    for (int kh = 0; kh < 11; ++kh) {
      int h = ho * 3 + kh;
      const float4* xr = (const float4*)(x + ((b * 3 + ci) * 112 + h) * 112 + a0);
      float w_[11];
#pragma unroll
      for (int kw = 0; kw < 11; ++kw)
        w_[kw] = c1wT[((ci * 11 + kh) * 11 + kw) * 256 + co];
      float rr[64];
#pragma unroll
      for (int q = 0; q < 16; ++q) {
        float4 v = xr[q];
        rr[4 * q] = v.x; rr[4 * q + 1] = v.y; rr[4 * q + 2] = v.z; rr[4 * q + 3] = v.w;
      }
#pragma unroll
      for (int w = 0; w < 17; ++w)
#pragma unroll
        for (int kw = 0; kw < 11; ++kw)
          acc[w] += w_[kw] * rr[3 * w + kw + OFF];
    }
  }
  __shared__ float ot[256 * 17];
#pragma unroll
  for (int w = 0; w < 17; ++w) ot[co * 17 + w] = fmaxf(acc[w], 0.f);
  __syncthreads();
  for (int it = 0; it < 17; ++it) {
    int idx = it * 256 + threadIdx.x;
    int c2 = idx / 17, w2 = idx - c2 * 17;
    feat[((b * 256 + c2) * 34 + ho) * 36 + wobase + w2] = ot[idx];
  }
}

// ---------------- primary caps conv: bf16 MFMA implicit-im2col GEMM ----------------
__global__ __launch_bounds__(256) void k_pc2(const float* __restrict__ feat,
                                             const unsigned short* __restrict__ PCWB,
                                             float* __restrict__ pcp) {
  __shared__ unsigned short sh[64 * 104 + 256 * 104];
  unsigned short* lA = sh;
  unsigned short* lB = sh + 64 * 104;

  int mb = blockIdx.x, kc = blockIdx.y;
  int t = threadIdx.x;
  int lane = t & 63, wv = t >> 6;
  int l15 = lane & 15, lh = lane >> 4;

  {
    uint4 zz = make_uint4(0, 0, 0, 0);
    uint4* z = (uint4*)sh;
    for (int i = t; i < (64 * 104 + 256 * 104) / 8; i += 256) z[i] = zz;
  }
  __syncthreads();

  f32x4 acc[4][4];
#pragma unroll
  for (int mf = 0; mf < 4; ++mf)
#pragma unroll
    for (int nf = 0; nf < 4; ++nf) acc[mf][nf] = (f32x4){0.f, 0.f, 0.f, 0.f};

  const unsigned short* arow = lA + l15 * 104 + lh * 8;
  const unsigned short* brow = lB + (wv * 64 + l15) * 104 + lh * 8;

#pragma unroll 1
  for (int cil = 0; cil < 32; ++cil) {
    int ci = kc * 32 + cil;
    {
      const unsigned short* Bsrc = PCWB + (size_t)ci * 26624;
#pragma unroll
      for (int i = 0; i < 13; ++i) {
        int f = i * 256 + t;
        ((uint4*)lB)[f] = *(const uint4*)(Bsrc + (size_t)f * 8);
      }
    }
    for (int task = t; task < 576; task += 256) {
      int m = task / 9, kh = task - m * 9;
      int gm = mb * 64 + m;
      if (gm < 2592) {
        int b = gm / 81, p = gm - b * 81;
        int ho = p / 9, wo = p - ho * 9;
        const float* src = feat + (size_t)((b * 256 + ci) * 34 + ho * 3 + kh) * 36 + wo * 3;
        unsigned short* dst = lA + m * 104 + kh * 9;
#pragma unroll
        for (int j = 0; j < 9; ++j) dst[j] = f2b(src[j]);
      }
    }
    __syncthreads();

#pragma unroll
    for (int s = 0; s < 3; ++s) {
      short8 a0 = *(const short8*)(arow + s * 32);
      short8 a1 = *(const short8*)(arow + 16 * 104 + s * 32);
      short8 a2 = *(const short8*)(arow + 32 * 104 + s * 32);
      short8 a3 = *(const short8*)(arow + 48 * 104 + s * 32);
      short8 b0 = *(const short8*)(brow + s * 32);
      short8 b1 = *(const short8*)(brow + 16 * 104 + s * 32);
      short8 b2 = *(const short8*)(brow + 32 * 104 + s * 32);
      short8 b3 = *(const short8*)(brow + 48 * 104 + s * 32);
      acc[0][0] = __builtin_amdgcn_mfma_f32_16x16x32_bf16(a0, b0, acc[0][0], 0, 0, 0);
      acc[0][1] = __builtin_amdgcn_mfma_f32_16x16x32_bf16(a0, b1, acc[0][1], 0, 0, 0);
      acc[0][2] = __builtin_amdgcn_mfma_f32_16x16x32_bf16(a0, b2, acc[0][2], 0, 0, 0);
      acc[0][3] = __builtin_amdgcn_mfma_f32_16x16x32_bf16(a0, b3, acc[0][3], 0, 0, 0);
      acc[1][0] = __builtin_amdgcn_mfma_f32_16x16x32_bf16(a1, b0, acc[1][0], 0, 0, 0);
      acc[1][1] = __builtin_amdgcn_mfma_f32_16x16x32_bf16(a1, b1, acc[1][1], 0, 0, 0);
      acc[1][2] = __builtin_amdgcn_mfma_f32_16x16x32_bf16(a1, b2, acc[1][2], 0, 0, 0);
      acc[1][3] = __builtin_amdgcn_mfma_f32_16x16x32_bf16(a1, b3, acc[1][3], 0, 0, 0);
      acc[2][0] = __builtin_amdgcn_mfma_f32_16x16x32_bf16(a2, b0, acc[2][0], 0, 0, 0);
      acc[2][1] = __builtin_amdgcn_mfma_f32_16x16x32_bf16(a2, b1, acc[2][1], 0, 0, 0);
      acc[2][2] = __builtin_amdgcn_mfma_f32_16x16x32_bf16(a2, b2, acc[2][2], 0, 0, 0);
      acc[2][3] = __builtin_amdgcn_mfma_f32_16x16x32_bf16(a2, b3, acc[2][3], 0, 0, 0);
      acc[3][0] = __builtin_amdgcn_mfma_f32_16x16x32_bf16(a3, b0, acc[3][0], 0, 0, 0);
      acc[3][1] = __builtin_amdgcn_mfma_f32_16x16x32_bf16(a3, b1, acc[3][1], 0, 0, 0);
      acc[3][2] = __builtin_amdgcn_mfma_f32_16x16x32_bf16(a3, b2, acc[3][2], 0, 0, 0);
      acc[3][3] = __builtin_amdgcn_mfma_f32_16x16x32_bf16(a3, b3, acc[3][3], 0, 0, 0);
    }
    __syncthreads();
  }

#pragma unroll
  for (int mf = 0; mf < 4; ++mf) {
    int gm = mb * 64 + mf * 16 + lh * 4;
    if (gm < 2592) {
      float* dst = pcp + (size_t)kc * 663552 + (size_t)gm * 256 + wv * 64 + l15;
#pragma unroll
      for (int nf = 0; nf < 4; ++nf)
#pragma unroll
        for (int r = 0; r < 4; ++r)
          dst[(size_t)r * 256 + nf * 16] = acc[mf][nf][r];
    }
  }
}

// sum 8 ci-chunk partials + bias
__global__ void k_pcreduce(const float* __restrict__ pcp,
                           const float* __restrict__ pcb,
                           float* __restrict__ pc2) {
  int i = blockIdx.x * 256 + threadIdx.x;
  float s = pcb[i & 255];
#pragma unroll
  for (int c = 0; c < 8; ++c) s += pcp[c * 663552 + i];
  pc2[i] = s;
}

// squash u (dim 8) -> u2[b][n][i]
__global__ void k_squash(const float* __restrict__ pc2, float* __restrict__ u2) {
  int t = blockIdx.x * 256 + threadIdx.x;  // < 82944
  int b = t / 2592, n = t - b * 2592;
  float v[8];
  float sq = 0.f;
#pragma unroll
  for (int i = 0; i < 8; ++i) {
    int f = n * 8 + i;
    int co = f / 81, p = f - co * 81;
    v[i] = pc2[(b * 81 + p) * 256 + co];
    sq += v[i] * v[i];
  }
  float sc = (sq / (1.f + sq)) / sqrtf(sq + 1e-8f);
#pragma unroll
  for (int i = 0; i < 8; ++i) u2[t * 8 + i] = v[i] * sc;
}

// ---------------- routing kernel A: logits + softmax -> cT[o][n][b] fp16 ----------------
__global__ __launch_bounds__(128) void k_A(const float* __restrict__ W,
                                           const float* __restrict__ u2,
                                           const float* __restrict__ vsum,
                                           __half* __restrict__ cT) {
  __shared__ float red[102 * 33];
  __shared__ float r2[4 * 33];
  __shared__ float ctile[102 * 33 * 3];
  int o = threadIdx.x;
  int nb = blockIdx.x;  // 864

  for (int nt = 0; nt < 3; ++nt) {
    int n = nb * 3 + nt;
    if (o < 102) {
      float4 wf[32];
      const float4* wp = (const float4*)(W + (size_t)(o * 2592 + n) * 128);
#pragma unroll
      for (int q = 0; q < 32; ++q) wf[q] = wp[q];
#pragma unroll 1
      for (int b = 0; b < 32; ++b) {
        float vr[16];
        {
          const float4* vp = (const float4*)(vsum + (b * 102 + o) * 16);
          float4 q0 = vp[0], q1 = vp[1], q2 = vp[2], q3 = vp[3];
          vr[0] = q0.x; vr[1] = q0.y; vr[2] = q0.z; vr[3] = q0.w;
          vr[4] = q1.x; vr[5] = q1.y; vr[6] = q1.z; vr[7] = q1.w;
          vr[8] = q2.x; vr[9] = q2.y; vr[10] = q2.z; vr[11] = q2.w;
          vr[12] = q3.x; vr[13] = q3.y; vr[14] = q3.z; vr[15] = q3.w;
        }
        float tt[8] = {0, 0, 0, 0, 0, 0, 0, 0};
#pragma unroll
        for (int d = 0; d < 16; ++d) {
          float vd = vr[d];
          float4 wa = wf[2 * d], wb = wf[2 * d + 1];
          tt[0] += wa.x * vd; tt[1] += wa.y * vd; tt[2] += wa.z * vd; tt[3] += wa.w * vd;
          tt[4] += wb.x * vd; tt[5] += wb.y * vd; tt[6] += wb.z * vd; tt[7] += wb.w * vd;
        }
        const float4* up = (const float4*)(u2 + (size_t)(b * 2592 + n) * 8);
        float4 ua = up[0], ub = up[1];
        float dlt = tt[0] * ua.x + tt[1] * ua.y + tt[2] * ua.z + tt[3] * ua.w +
                    tt[4] * ub.x + tt[5] * ub.y + tt[6] * ub.z + tt[7] * ub.w;
        red[o * 33 + b] = __expf(dlt);
      }
    }
    __syncthreads();
    {
      int bb = threadIdx.x & 31, g = threadIdx.x >> 5;
      float ps = 0.f;
      int oend = (g * 26 + 26 < 102) ? g * 26 + 26 : 102;
      for (int oo = g * 26; oo < oend; ++oo) ps += red[oo * 33 + bb];
      r2[g * 33 + bb] = ps;
    }
    __syncthreads();
    if (threadIdx.x < 32) {
      int bb = threadIdx.x;
      r2[bb] = 1.0f / (r2[bb] + r2[33 + bb] + r2[66 + bb] + r2[99 + bb]);
    }
    __syncthreads();
    if (o < 102) {
#pragma unroll 1
      for (int b = 0; b < 32; ++b)
        ctile[(o * 33 + b) * 3 + nt] = red[o * 33 + b] * r2[b];
    }
    __syncthreads();
  }
  // write cT[o][n][b] fp16 (consecutive idx -> consecutive b -> 64B runs)
  for (int it = 0; it < 26; ++it) {
    int idx = it * 128 + threadIdx.x;
    if (idx < 3264) {
      int oo = idx >> 5, bb = idx & 31;
      __half* dst = cT + ((size_t)oo * 2592 + nb * 3) * 32 + bb;
      dst[0]  = __float2half(ctile[(oo * 33 + bb) * 3 + 0]);
      dst[32] = __float2half(ctile[(oo * 33 + bb) * 3 + 1]);
      dst[64] = __float2half(ctile[(oo * 33 + bb) * 3 + 2]);
    }
  }
}

// ---------------- routing kernel B (MFMA): s[b,o,d] += sum_{n,i} (c*u)*W ----------------
// Per o: GEMM D[d=16][b=32], K=(n,i)=20736. A = Wb[o][n][d][i] (lane: row d=l&15,
// k-chunk h=l>>4 -> n=n0+h, i=0..7 -> contiguous 16B). B = bf16(c*u) built in-reg.
// grid (102, 8); block 256 = 4 waves interleaving the 81 K-steps of this chunk.
__device__ __forceinline__ short8 cu_pack(float c, float4 a, float4 b) {
  short8 r;
  r[0] = (short)f2b(c * a.x); r[1] = (short)f2b(c * a.y);
  r[2] = (short)f2b(c * a.z); r[3] = (short)f2b(c * a.w);
  r[4] = (short)f2b(c * b.x); r[5] = (short)f2b(c * b.y);
  r[6] = (short)f2b(c * b.z); r[7] = (short)f2b(c * b.w);
  return r;
}

template <bool HASC>
__global__ __launch_bounds__(256) void k_B2(const unsigned short* __restrict__ Wb,
                                            const float* __restrict__ u2,
                                            const __half* __restrict__ cT,
                                            float* __restrict__ s) {
  int o = blockIdx.x, kc = blockIdx.y;
  int t = threadIdx.x, lane = t & 63, wv = t >> 6;
  int l15 = lane & 15, h = lane >> 4;

  f32x4 acc0 = {0.f, 0.f, 0.f, 0.f}, acc1 = {0.f, 0.f, 0.f, 0.f};

#pragma unroll 1
  for (int st = wv; st < 81; st += 4) {
    int n = kc * 324 + st * 4 + h;
    short8 af = *(const short8*)(Wb + (((size_t)o * 2592 + n) * 16 + l15) * 8);

    const float4* u0p = (const float4*)(u2 + ((size_t)l15 * 2592 + n) * 8);
    float4 u0a = u0p[0], u0b = u0p[1];
    const float4* u1p = (const float4*)(u2 + ((size_t)(l15 + 16) * 2592 + n) * 8);
    float4 u1a = u1p[0], u1b = u1p[1];

    float c0 = 1.0f, c1 = 1.0f;
    if (HASC) {
      const __half* cp = cT + ((size_t)o * 2592 + n) * 32;
      c0 = __half2float(cp[l15]);
      c1 = __half2float(cp[l15 + 16]);
    }
    short8 bf0 = cu_pack(c0, u0a, u0b);
    short8 bf1 = cu_pack(c1, u1a, u1b);

    acc0 = __builtin_amdgcn_mfma_f32_16x16x32_bf16(af, bf0, acc0, 0, 0, 0);
    acc1 = __builtin_amdgcn_mfma_f32_16x16x32_bf16(af, bf1, acc1, 0, 0, 0);
  }

  // D: row d = h*4+r (from A), col b = l15 (+16 for acc1, from B)
#pragma unroll
  for (int r = 0; r < 4; ++r) {
    atomicAdd(s + ((size_t)l15 * 102 + o) * 16 + h * 4 + r, acc0[r]);
    atomicAdd(s + ((size_t)(l15 + 16) * 102 + o) * 16 + h * 4 + r, acc1[r]);
  }
}

// ---------------- squash v (dim 16), optional vsum ----------------
__global__ void k_R(const float* __restrict__ s, float scale,
                    float* __restrict__ vout, const float* __restrict__ v0in,
                    float* __restrict__ vsout) {
  int t = blockIdx.x * 256 + threadIdx.x;
  if (t >= 3264) return;
  const float* sp = s + t * 16;
  float r[16];
  float sq = 0.f;
#pragma unroll
  for (int d = 0; d < 16; ++d) {
    r[d] = sp[d] * scale;
    sq += r[d] * r[d];
  }
  float sc = (sq / (1.f + sq)) / sqrtf(sq + 1e-8f);
#pragma unroll
  for (int d = 0; d < 16; ++d) {
    float vv = r[d] * sc;
    vout[t * 16 + d] = vv;
    if (vsout) vsout[t * 16 + d] = v0in[t * 16 + d] + vv;
  }
}

// ---------------- fc chain ----------------
__global__ void k_fc1(const float* __restrict__ v2, const int* __restrict__ tgt,
                      const float* __restrict__ w1, const float* __restrict__ b1,
                      float* __restrict__ h1) {
  int j = blockIdx.x * 128 + threadIdx.x;  // < 512
  int bq = blockIdx.y;
#pragma unroll
  for (int bi = 0; bi < 4; ++bi) {
    int b = bq * 4 + bi;
    int tb = tgt[b];
    float acc = b1[j];
    const float* vv = v2 + (b * 102 + tb) * 16;
    const float* wr = w1 + (tb * 16) * 512 + j;
#pragma unroll
    for (int d = 0; d < 16; ++d) acc += vv[d] * wr[d * 512];
    h1[b * 512 + j] = fmaxf(acc, 0.f);
  }
}

__global__ void k_fc2(const float* __restrict__ h1, const float* __restrict__ w2,
                      const float* __restrict__ b2, float* __restrict__ h2T) {
  int j = blockIdx.x * 128 + threadIdx.x;  // < 1024
  int bq = blockIdx.y;
  float acc[4];
#pragma unroll
  for (int bi = 0; bi < 4; ++bi) acc[bi] = b2[j];
  for (int k = 0; k < 512; ++k) {
    float wv = w2[k * 1024 + j];
#pragma unroll
    for (int bi = 0; bi < 4; ++bi) acc[bi] += h1[(bq * 4 + bi) * 512 + k] * wv;
  }
  float4 o;
  o.x = fmaxf(acc[0], 0.f); o.y = fmaxf(acc[1], 0.f);
  o.z = fmaxf(acc[2], 0.f); o.w = fmaxf(acc[3], 0.f);
  *(float4*)(h2T + j * 32 + bq * 4) = o;
}

__global__ void k_fc3(const float* __restrict__ h2T, const float* __restrict__ w3,
                      const float* __restrict__ b3, float* __restrict__ out) {
  int j = blockIdx.x * 128 + threadIdx.x;  // < 37632
  int bq = blockIdx.y;
  float acc[8];
  float bv = b3[j];
#pragma unroll
  for (int i = 0; i < 8; ++i) acc[i] = bv;
  for (int k = 0; k < 1024; ++k) {
    float wv = w3[(size_t)k * 37632 + j];
    const float4* hp = (const float4*)(h2T + k * 32 + bq * 8);
    float4 ha = hp[0], hb = hp[1];
    acc[0] += ha.x * wv; acc[1] += ha.y * wv; acc[2] += ha.z * wv; acc[3] += ha.w * wv;
    acc[4] += hb.x * wv; acc[5] += hb.y * wv; acc[6] += hb.z * wv; acc[7] += hb.w * wv;
  }
#pragma unroll
  for (int i = 0; i < 8; ++i) {
    float sg = 1.0f / (1.0f + __expf(-acc[i]));
    out[52224 + (size_t)(bq * 8 + i) * 37632 + j] = sg;
  }
}

// ---------------- host ----------------
extern "C" void kernel_launch(void* const* d_in, const int* in_sizes, int n_in,
                              void* d_out, int out_size, void* d_ws, size_t ws_size,
                              hipStream_t stream) {
  const float* x       = (const float*)d_in[0];
  const int*   targets = (const int*)d_in[1];
  const float* conv1_w = (const float*)d_in[2];
  const float* conv1_b = (const float*)d_in[3];
  const float* pc_w    = (const float*)d_in[4];
  const float* pc_b    = (const float*)d_in[5];
  const float* W       = (const float*)d_in[6];
  const float* fc1_w   = (const float*)d_in[7];
  const float* fc1_b   = (const float*)d_in[8];
  const float* fc2_w   = (const float*)d_in[9];
  const float* fc2_b   = (const float*)d_in[10];
  const float* fc3_w   = (const float*)d_in[11];
  const float* fc3_b   = (const float*)d_in[12];
  float* out = (float*)d_out;
  float* ws = (float*)d_ws;

  float* FEAT = ws + OFF_FEAT;
  float* C1WT = ws + OFF_C1WT;
  unsigned short* PCWB = (unsigned short*)(ws + OFF_PCWT);
  float* PCP  = ws + OFF_PCP;
  float* PC2  = ws + OFF_PC2;
  float* U2   = ws + OFF_U2;
  unsigned short* WB = (unsigned short*)(ws + OFF_FEAT);  // overlays FEAT+C1WT+PCWB+lowPCP after squash
  __half* CT  = (__half*)(ws + OFF_CT);
  float* S    = ws + OFF_S;
  float* V0   = ws + OFF_V0;
  float* V1   = ws + OFF_V1;
  float* VS   = ws + OFF_VS;
  float* H1   = ws + OFF_H1;
  float* H2T  = ws + OFF_H2T;

  // weight prep
  k_wtrans<<<dim3(6, 4), 256, 0, stream>>>(conv1_w, C1WT, 256, 363);
  k_mkB<<<dim3(256), 256, 0, stream>>>(pc_w, PCWB);

  // conv1 + relu
  k_conv1<0><<<dim3(34 * 32), 256, 0, stream>>>(x, C1WT, conv1_b, FEAT);
  k_conv1<3><<<dim3(34 * 32), 256, 0, stream>>>(x, C1WT, conv1_b, FEAT);

  // primary caps conv + reduce + bias + squash
  k_pc2<<<dim3(41, 8), 256, 0, stream>>>(FEAT, PCWB, PCP);
  k_pcreduce<<<dim3(2592), 256, 0, stream>>>(PCP, pc_b, PC2);
  k_squash<<<dim3(324), 256, 0, stream>>>(PC2, U2);

  // routing W -> bf16 (FEAT region now dead)
  k_mkWb<<<dim3(16537), 256, 0, stream>>>(W, WB);

  // ---- routing ----
  hipMemsetAsync(S, 0, 52224 * sizeof(float), stream);
  k_B2<false><<<dim3(102, 8), 256, 0, stream>>>(WB, U2, nullptr, S);
  k_R<<<dim3(13), 256, 0, stream>>>(S, 1.0f / 102.0f, V0, nullptr, nullptr);

  k_A<<<dim3(864), 128, 0, stream>>>(W, U2, V0, CT);
  hipMemsetAsync(S, 0, 52224 * sizeof(float), stream);
  k_B2<true><<<dim3(102, 8), 256, 0, stream>>>(WB, U2, CT, S);
  k_R<<<dim3(13), 256, 0, stream>>>(S, 1.0f, V1, V0, VS);  // VS = v0 + v1

  k_A<<<dim3(864), 128, 0, stream>>>(W, U2, VS, CT);
  hipMemsetAsync(S, 0, 52224 * sizeof(float), stream);
  k_B2<true><<<dim3(102, 8), 256, 0, stream>>>(WB, U2, CT, S);
  k_R<<<dim3(13), 256, 0, stream>>>(S, 1.0f, out, nullptr, nullptr);

  // ---- reconstruction ----
  k_fc1<<<dim3(4, 8), 128, 0, stream>>>(out, targets, fc1_w, fc1_b, H1);
  k_fc2<<<dim3(8, 8), 128, 0, stream>>>(H1, fc2_w, fc2_b, H2T);
  k_fc3<<<dim3(294, 4), 128, 0, stream>>>(H2T, fc3_w, fc3_b, out);
}

// Round 4
// 943.639 us; speedup vs baseline: 2.6492x; 1.0374x over previous
//
#include <hip/hip_runtime.h>
#include <hip/hip_fp16.h>
#include <math.h>

// ---------------- sizes ----------------
#define B32   32
#define OCLS  102
#define NCAPS 2592
#define DIN   8
#define DOUT  16

// ---------------- ws map (floats) ----------------
// phase 1 (conv/pc): FEAT C1WT PCWB PCP PC2 U2
// phase 2 (routing): WB(bf16) [0,16933888) overlays FEAT/C1WT/PCWB/PCP-low
//                    WB2Q(fp8) [16933888,25400832) overlays PCP-high/PC2
//                    (all dead after k_squash; packs run after k_squash)
#define OFF_FEAT   0u               // 32*256*34*36 = 10,027,008
#define OFF_C1WT   10027008u        // 363*256      =     92,928
#define OFF_PCWT   10119936u        // bf16 pc pack: 256*256*104 ush
#define OFF_PCP    15428352u        // 8*32*81*256  =  5,308,416
#define OFF_PC2    20736768u        // 32*81*256    =    663,552
#define OFF_WB2Q   16933888u        // fp8 W pack [o][n][i][d]: 33,867,776 B
#define OFF_U2     25400832u        // 32*2592*8    =    663,552
#define OFF_CT     26064384u        // fp16 c[o][n][b]: 8,460,288 halfs
#define OFF_S      30294528u        // 32*102*16
#define OFF_V0     30346752u
#define OFF_V1     30398976u
#define OFF_VSQ    30451200u        // fp8 vsum[o][b][d]: 52,224 B
#define OFF_H1     30464256u        // 32*512
#define OFF_H2T    30480640u        // 1024*32  -> end 30,513,408

typedef __attribute__((ext_vector_type(8))) short short8;
typedef __attribute__((ext_vector_type(4))) float f32x4;
typedef long long i64;

__device__ __forceinline__ unsigned short f2b(float f) {
  union { float f; unsigned u; } v; v.f = f;
  unsigned r = v.u + 0x7fffu + ((v.u >> 16) & 1u);
  return (unsigned short)(r >> 16);
}

// float -> OCP e4m3fn (RNE), manual (no header/builtin dependency)
__device__ __forceinline__ unsigned char f2q(float f) {
  float a = fabsf(f);
  unsigned char s = (f < 0.f) ? 0x80 : 0;
  if (!(a < 448.f)) return s | 0x7E;            // clamp to max finite (and NaN->max)
  if (a < 0.0009765625f) return s;              // < half of min subnormal -> 0
  if (a < 0.015625f) {                          // subnormal: quantum 2^-9
    int q = (int)rintf(a * 512.f);
    if (q >= 8) return s | 0x08;                // rounds up to min normal
    return s | (unsigned char)q;
  }
  int eb;
  frexpf(a, &eb);
  int E = eb - 1;                               // a = m*2^E, m in [1,2)
  float m = ldexpf(a, -E);
  int mm = (int)rintf(m * 8.f);
  if (mm >= 16) { mm = 8; E += 1; }
  return s | (unsigned char)(((E + 7) << 3) | (mm - 8));
}

// ---------------- weight transpose [CO][K] -> [K][CO] (conv1 only) ----------------
__global__ void k_wtrans(const float* __restrict__ in, float* __restrict__ out,
                         int CO, int K) {
  __shared__ float t[64][65];
  int kb = blockIdx.x * 64, cb = blockIdx.y * 64;
  int tx = threadIdx.x & 63, ty = threadIdx.x >> 6;
  for (int r = ty; r < 64; r += 4) {
    int co = cb + r, k = kb + tx;
    t[r][tx] = (k < K) ? in[(size_t)co * K + k] : 0.f;
  }
  __syncthreads();
  for (int r = ty; r < 64; r += 4) {
    int k = kb + r, co = cb + tx;
    if (k < K) out[(size_t)k * CO + co] = t[tx][r];
  }
}

// ---------------- pc_w repack -> bf16 [ci][co][104] ----------------
__global__ void k_mkB(const float* __restrict__ pc_w, unsigned short* __restrict__ PCWB) {
  int co = blockIdx.x;
  for (int e = threadIdx.x; e < 20736; e += 256) {
    int ci = e / 81, tap = e - ci * 81;
    PCWB[(size_t)ci * 26624 + co * 104 + tap] = f2b(pc_w[(size_t)co * 20736 + e]);
  }
  int ci = threadIdx.x;
  for (int tap = 81; tap < 104; ++tap)
    PCWB[(size_t)ci * 26624 + co * 104 + tap] = 0;
}

// ---------------- routing W -> bf16 Wb[o][n][d][i] (same element order) ----------------
__global__ void k_mkWb(const float* __restrict__ W, unsigned short* __restrict__ Wb) {
  size_t i = ((size_t)blockIdx.x * 256 + threadIdx.x) * 8;
  const float4* p = (const float4*)(W + i);
  float4 a = p[0], b = p[1];
  unsigned u0 = (unsigned)f2b(a.x) | ((unsigned)f2b(a.y) << 16);
  unsigned u1 = (unsigned)f2b(a.z) | ((unsigned)f2b(a.w) << 16);
  unsigned u2 = (unsigned)f2b(b.x) | ((unsigned)f2b(b.y) << 16);
  unsigned u3 = (unsigned)f2b(b.z) | ((unsigned)f2b(b.w) << 16);
  *(uint4*)(Wb + i) = make_uint4(u0, u1, u2, u3);
}

// ---------------- routing W -> fp8 Wq[o][n][i][d] (d/i transposed) ----------------
__global__ void k_mkWq(const float* __restrict__ W, unsigned char* __restrict__ Wq) {
  int on = blockIdx.x * 256 + threadIdx.x;  // (o,n) pairs: 264,384
  if (on >= 102 * 2592) return;
  const float* src = W + (size_t)on * 128;
  unsigned words[8][4];
#pragma unroll
  for (int i = 0; i < 8; ++i)
#pragma unroll
    for (int w = 0; w < 4; ++w) words[i][w] = 0;
#pragma unroll
  for (int d = 0; d < 16; ++d) {
    const float4* p = (const float4*)(src + d * 8);
    float4 a = p[0], b = p[1];
    float vals[8] = {a.x, a.y, a.z, a.w, b.x, b.y, b.z, b.w};
#pragma unroll
    for (int i = 0; i < 8; ++i)
      words[i][d >> 2] |= ((unsigned)f2q(vals[i])) << ((d & 3) * 8);
  }
  uint4* dst = (uint4*)(Wq + (size_t)on * 128);
#pragma unroll
  for (int i = 0; i < 8; ++i)
    dst[i] = make_uint4(words[i][0], words[i][1], words[i][2], words[i][3]);
}

// ---------------- conv1 11x11 s3 + bias + relu ----------------
template <int OFF>
__global__ __launch_bounds__(256) void k_conv1(const float* __restrict__ x,
                                               const float* __restrict__ c1wT,
                                               const float* __restrict__ bias,
                                               float* __restrict__ feat) {
  int bx = blockIdx.x;
  int ho = bx % 34, b = bx / 34;
  int co = threadIdx.x;
  const int wobase = (OFF == 0) ? 0 : 17;
  const int a0 = (OFF == 0) ? 0 : 48;

  float bv = bias[co];
  float acc[17];
#pragma unroll
  for (int w = 0; w < 17; ++w) acc[w] = bv;

#pragma unroll 1
  for (int ci = 0; ci < 3; ++ci) {
#pragma unroll 1
    for (int kh = 0; kh < 11; ++kh) {
      int h = ho * 3 + kh;
      const float4* xr = (const float4*)(x + ((b * 3 + ci) * 112 + h) * 112 + a0);
      float w_[11];
#pragma unroll
      for (int kw = 0; kw < 11; ++kw)
        w_[kw] = c1wT[((ci * 11 + kh) * 11 + kw) * 256 + co];
      float rr[64];
#pragma unroll
      for (int q = 0; q < 16; ++q) {
        float4 v = xr[q];
        rr[4 * q] = v.x; rr[4 * q + 1] = v.y; rr[4 * q + 2] = v.z; rr[4 * q + 3] = v.w;
      }
#pragma unroll
      for (int w = 0; w < 17; ++w)
#pragma unroll
        for (int kw = 0; kw < 11; ++kw)
          acc[w] += w_[kw] * rr[3 * w + kw + OFF];
    }
  }
  __shared__ float ot[256 * 17];
#pragma unroll
  for (int w = 0; w < 17; ++w) ot[co * 17 + w] = fmaxf(acc[w], 0.f);
  __syncthreads();
  for (int it = 0; it < 17; ++it) {
    int idx = it * 256 + threadIdx.x;
    int c2 = idx / 17, w2 = idx - c2 * 17;
    feat[((b * 256 + c2) * 34 + ho) * 36 + wobase + w2] = ot[idx];
  }
}

// ---------------- primary caps conv: bf16 MFMA implicit-im2col GEMM ----------------
__global__ __launch_bounds__(256) void k_pc2(const float* __restrict__ feat,
                                             const unsigned short* __restrict__ PCWB,
                                             float* __restrict__ pcp) {
  __shared__ unsigned short sh[64 * 104 + 256 * 104];
  unsigned short* lA = sh;
  unsigned short* lB = sh + 64 * 104;

  int mb = blockIdx.x, kc = blockIdx.y;
  int t = threadIdx.x;
  int lane = t & 63, wv = t >> 6;
  int l15 = lane & 15, lh = lane >> 4;

  {
    uint4 zz = make_uint4(0, 0, 0, 0);
    uint4* z = (uint4*)sh;
    for (int i = t; i < (64 * 104 + 256 * 104) / 8; i += 256) z[i] = zz;
  }
  __syncthreads();

  f32x4 acc[4][4];
#pragma unroll
  for (int mf = 0; mf < 4; ++mf)
#pragma unroll
    for (int nf = 0; nf < 4; ++nf) acc[mf][nf] = (f32x4){0.f, 0.f, 0.f, 0.f};

  const unsigned short* arow = lA + l15 * 104 + lh * 8;
  const unsigned short* brow = lB + (wv * 64 + l15) * 104 + lh * 8;

#pragma unroll 1
  for (int cil = 0; cil < 32; ++cil) {
    int ci = kc * 32 + cil;
    {
      const unsigned short* Bsrc = PCWB + (size_t)ci * 26624;
#pragma unroll
      for (int i = 0; i < 13; ++i) {
        int f = i * 256 + t;
        ((uint4*)lB)[f] = *(const uint4*)(Bsrc + (size_t)f * 8);
      }
    }
    for (int task = t; task < 576; task += 256) {
      int m = task / 9, kh = task - m * 9;
      int gm = mb * 64 + m;
      if (gm < 2592) {
        int b = gm / 81, p = gm - b * 81;
        int ho = p / 9, wo = p - ho * 9;
        const float* src = feat + (size_t)((b * 256 + ci) * 34 + ho * 3 + kh) * 36 + wo * 3;
        unsigned short* dst = lA + m * 104 + kh * 9;
#pragma unroll
        for (int j = 0; j < 9; ++j) dst[j] = f2b(src[j]);
      }
    }
    __syncthreads();

#pragma unroll
    for (int s = 0; s < 3; ++s) {
      short8 a0 = *(const short8*)(arow + s * 32);
      short8 a1 = *(const short8*)(arow + 16 * 104 + s * 32);
      short8 a2 = *(const short8*)(arow + 32 * 104 + s * 32);
      short8 a3 = *(const short8*)(arow + 48 * 104 + s * 32);
      short8 b0 = *(const short8*)(brow + s * 32);
      short8 b1 = *(const short8*)(brow + 16 * 104 + s * 32);
      short8 b2 = *(const short8*)(brow + 32 * 104 + s * 32);
      short8 b3 = *(const short8*)(brow + 48 * 104 + s * 32);
      acc[0][0] = __builtin_amdgcn_mfma_f32_16x16x32_bf16(a0, b0, acc[0][0], 0, 0, 0);
      acc[0][1] = __builtin_amdgcn_mfma_f32_16x16x32_bf16(a0, b1, acc[0][1], 0, 0, 0);
      acc[0][2] = __builtin_amdgcn_mfma_f32_16x16x32_bf16(a0, b2, acc[0][2], 0, 0, 0);
      acc[0][3] = __builtin_amdgcn_mfma_f32_16x16x32_bf16(a0, b3, acc[0][3], 0, 0, 0);
      acc[1][0] = __builtin_amdgcn_mfma_f32_16x16x32_bf16(a1, b0, acc[1][0], 0, 0, 0);
      acc[1][1] = __builtin_amdgcn_mfma_f32_16x16x32_bf16(a1, b1, acc[1][1], 0, 0, 0);
      acc[1][2] = __builtin_amdgcn_mfma_f32_16x16x32_bf16(a1, b2, acc[1][2], 0, 0, 0);
      acc[1][3] = __builtin_amdgcn_mfma_f32_16x16x32_bf16(a1, b3, acc[1][3], 0, 0, 0);
      acc[2][0] = __builtin_amdgcn_mfma_f32_16x16x32_bf16(a2, b0, acc[2][0], 0, 0, 0);
      acc[2][1] = __builtin_amdgcn_mfma_f32_16x16x32_bf16(a2, b1, acc[2][1], 0, 0, 0);
      acc[2][2] = __builtin_amdgcn_mfma_f32_16x16x32_bf16(a2, b2, acc[2][2], 0, 0, 0);
      acc[2][3] = __builtin_amdgcn_mfma_f32_16x16x32_bf16(a2, b3, acc[2][3], 0, 0, 0);
      acc[3][0] = __builtin_amdgcn_mfma_f32_16x16x32_bf16(a3, b0, acc[3][0], 0, 0, 0);
      acc[3][1] = __builtin_amdgcn_mfma_f32_16x16x32_bf16(a3, b1, acc[3][1], 0, 0, 0);
      acc[3][2] = __builtin_amdgcn_mfma_f32_16x16x32_bf16(a3, b2, acc[3][2], 0, 0, 0);
      acc[3][3] = __builtin_amdgcn_mfma_f32_16x16x32_bf16(a3, b3, acc[3][3], 0, 0, 0);
    }
    __syncthreads();
  }

#pragma unroll
  for (int mf = 0; mf < 4; ++mf) {
    int gm = mb * 64 + mf * 16 + lh * 4;
    if (gm < 2592) {
      float* dst = pcp + (size_t)kc * 663552 + (size_t)gm * 256 + wv * 64 + l15;
#pragma unroll
      for (int nf = 0; nf < 4; ++nf)
#pragma unroll
        for (int r = 0; r < 4; ++r)
          dst[(size_t)r * 256 + nf * 16] = acc[mf][nf][r];
    }
  }
}

// sum 8 ci-chunk partials + bias
__global__ void k_pcreduce(const float* __restrict__ pcp,
                           const float* __restrict__ pcb,
                           float* __restrict__ pc2) {
  int i = blockIdx.x * 256 + threadIdx.x;
  float s = pcb[i & 255];
#pragma unroll
  for (int c = 0; c < 8; ++c) s += pcp[c * 663552 + i];
  pc2[i] = s;
}

// squash u (dim 8) -> u2[b][n][i]
__global__ void k_squash(const float* __restrict__ pc2, float* __restrict__ u2) {
  int t = blockIdx.x * 256 + threadIdx.x;  // < 82944
  int b = t / 2592, n = t - b * 2592;
  float v[8];
  float sq = 0.f;
#pragma unroll
  for (int i = 0; i < 8; ++i) {
    int f = n * 8 + i;
    int co = f / 81, p = f - co * 81;
    v[i] = pc2[(b * 81 + p) * 256 + co];
    sq += v[i] * v[i];
  }
  float sc = (sq / (1.f + sq)) / sqrtf(sq + 1e-8f);
#pragma unroll
  for (int i = 0; i < 8; ++i) u2[t * 8 + i] = v[i] * sc;
}

// ---------------- routing kernel A (fp8 MFMA): logits + softmax -> cT[o][n][b] ----
// Block owns 4 n's (2 waves, each a n-pair). Per o: T[(nl,i)][b] = sum_d Wq*vq via
// 16x16x32 fp8 mfma (K = d16 + 16 zero-pad), then *u and shfl_xor(16) to finish
// the i-reduce. E staged in LDS; softmax over o block-local; cT written fp16.
__global__ __launch_bounds__(128) void k_A2(const unsigned char* __restrict__ Wq,
                                            const float* __restrict__ u2,
                                            const unsigned char* __restrict__ vq,
                                            __half* __restrict__ cT) {
  __shared__ __half Eld[102 * 2 * 2 * 32];
  int nb = blockIdx.x;  // 648
  int t = threadIdx.x, wv = t >> 6, lane = t & 63;
  int l15 = lane & 15, g = lane >> 4;
  int n0 = nb * 4 + 2 * wv;
  int nl = g >> 1, ih = (g & 1) * 4;

  // u fragments (o-independent): row m=g*4+r of D -> u[b][n0+nl][ih+r]
  float4 u0 = *(const float4*)(u2 + (((size_t)l15 * 2592 + n0 + nl) * 8 + ih));
  float4 u1 = *(const float4*)(u2 + (((size_t)(l15 + 16) * 2592 + n0 + nl) * 8 + ih));

  // A operand: row m=l15=(nlA*8+iA), k-chunk g (<2 real, else zero)
  int nlA = l15 >> 3, iA = l15 & 7;
  const unsigned char* Ap = Wq + (((size_t)(n0 + nlA)) * 8 + iA) * 16 + (g & 1) * 8;
  const unsigned char* B0p = vq + (size_t)l15 * 16 + (g & 1) * 8;
  bool act = (g < 2);

  float den0 = 0.f, den1 = 0.f;
#pragma unroll 2
  for (int o = 0; o < 102; ++o) {
    i64 a = 0, b0 = 0, b1 = 0;
    if (act) {
      a  = *(const i64*)(Ap + (size_t)o * 331776);
      b0 = *(const i64*)(B0p + (size_t)o * 512);
      b1 = *(const i64*)(B0p + (size_t)o * 512 + 256);
    }
    f32x4 d0 = {0.f, 0.f, 0.f, 0.f}, d1 = {0.f, 0.f, 0.f, 0.f};
    d0 = __builtin_amdgcn_mfma_f32_16x16x32_fp8_fp8(a, b0, d0, 0, 0, 0);
    d1 = __builtin_amdgcn_mfma_f32_16x16x32_fp8_fp8(a, b1, d1, 0, 0, 0);
    float p0 = d0[0] * u0.x + d0[1] * u0.y + d0[2] * u0.z + d0[3] * u0.w;
    float p1 = d1[0] * u1.x + d1[1] * u1.y + d1[2] * u1.z + d1[3] * u1.w;
    p0 += __shfl_xor(p0, 16);
    p1 += __shfl_xor(p1, 16);
    float e0 = __expf(p0), e1 = __expf(p1);
    den0 += e0; den1 += e1;
    if ((g & 1) == 0) {
      int base = (o * 2 + wv) * 64 + (g >> 1) * 16 + l15;
      Eld[base] = __float2half(e0);
      Eld[base + 32] = __float2half(e1);
    }
  }
  float r0 = 1.0f / den0, r1 = 1.0f / den1;
  if ((g & 1) == 0) {
    for (int o = 0; o < 102; ++o) {
      int base = (o * 2 + wv) * 64 + (g >> 1) * 16 + l15;
      float c0 = __half2float(Eld[base]) * r0;
      float c1 = __half2float(Eld[base + 32]) * r1;
      __half* dst = cT + ((size_t)o * 2592 + n0 + (g >> 1)) * 32 + l15;
      dst[0] = __float2half(c0);
      dst[16] = __float2half(c1);
    }
  }
}

// ---------------- routing kernel B (bf16 MFMA): s[b,o,d] += sum_{n,i} (c*u)*W ------
__device__ __forceinline__ short8 cu_pack(float c, float4 a, float4 b) {
  short8 r;
  r[0] = (short)f2b(c * a.x); r[1] = (short)f2b(c * a.y);
  r[2] = (short)f2b(c * a.z); r[3] = (short)f2b(c * a.w);
  r[4] = (short)f2b(c * b.x); r[5] = (short)f2b(c * b.y);
  r[6] = (short)f2b(c * b.z); r[7] = (short)f2b(c * b.w);
  return r;
}

template <bool HASC>
__global__ __launch_bounds__(256) void k_B2(const unsigned short* __restrict__ Wb,
                                            const float* __restrict__ u2,
                                            const __half* __restrict__ cT,
                                            float* __restrict__ s) {
  int o = blockIdx.x, kc = blockIdx.y;
  int t = threadIdx.x, lane = t & 63, wv = t >> 6;
  int l15 = lane & 15, h = lane >> 4;

  f32x4 acc0 = {0.f, 0.f, 0.f, 0.f}, acc1 = {0.f, 0.f, 0.f, 0.f};

#pragma unroll 1
  for (int st = wv; st < 81; st += 4) {
    int n = kc * 324 + st * 4 + h;
    short8 af = *(const short8*)(Wb + (((size_t)o * 2592 + n) * 16 + l15) * 8);

    const float4* u0p = (const float4*)(u2 + ((size_t)l15 * 2592 + n) * 8);
    float4 u0a = u0p[0], u0b = u0p[1];
    const float4* u1p = (const float4*)(u2 + ((size_t)(l15 + 16) * 2592 + n) * 8);
    float4 u1a = u1p[0], u1b = u1p[1];

    float c0 = 1.0f, c1 = 1.0f;
    if (HASC) {
      const __half* cp = cT + ((size_t)o * 2592 + n) * 32;
      c0 = __half2float(cp[l15]);
      c1 = __half2float(cp[l15 + 16]);
    }
    short8 bf0 = cu_pack(c0, u0a, u0b);
    short8 bf1 = cu_pack(c1, u1a, u1b);

    acc0 = __builtin_amdgcn_mfma_f32_16x16x32_bf16(af, bf0, acc0, 0, 0, 0);
    acc1 = __builtin_amdgcn_mfma_f32_16x16x32_bf16(af, bf1, acc1, 0, 0, 0);
  }

#pragma unroll
  for (int r = 0; r < 4; ++r) {
    atomicAdd(s + ((size_t)l15 * 102 + o) * 16 + h * 4 + r, acc0[r]);
    atomicAdd(s + ((size_t)(l15 + 16) * 102 + o) * 16 + h * 4 + r, acc1[r]);
  }
}

// ---------------- squash v (dim 16); optional fp8 vsum[o][b][d] output ----------------
__global__ void k_R(const float* __restrict__ s, float scale,
                    float* __restrict__ vout, const float* __restrict__ addin,
                    unsigned char* __restrict__ vsq) {
  int t = blockIdx.x * 256 + threadIdx.x;
  if (t >= 3264) return;
  const float* sp = s + t * 16;
  float r[16];
  float sq = 0.f;
#pragma unroll
  for (int d = 0; d < 16; ++d) {
    r[d] = sp[d] * scale;
    sq += r[d] * r[d];
  }
  float sc = (sq / (1.f + sq)) / sqrtf(sq + 1e-8f);
  float vv[16];
#pragma unroll
  for (int d = 0; d < 16; ++d) {
    vv[d] = r[d] * sc;
    vout[t * 16 + d] = vv[d];
  }
  if (vsq) {
    int b = t / 102, o = t - b * 102;
    unsigned words[4] = {0, 0, 0, 0};
#pragma unroll
    for (int d = 0; d < 16; ++d) {
      float w = addin ? (addin[t * 16 + d] + vv[d]) : vv[d];
      words[d >> 2] |= ((unsigned)f2q(w)) << ((d & 3) * 8);
    }
    *(uint4*)(vsq + ((size_t)o * 32 + b) * 16) =
        make_uint4(words[0], words[1], words[2], words[3]);
  }
}

// ---------------- fc chain ----------------
__global__ void k_fc1(const float* __restrict__ v2, const int* __restrict__ tgt,
                      const float* __restrict__ w1, const float* __restrict__ b1,
                      float* __restrict__ h1) {
  int j = blockIdx.x * 128 + threadIdx.x;  // < 512
  int bq = blockIdx.y;
#pragma unroll
  for (int bi = 0; bi < 4; ++bi) {
    int b = bq * 4 + bi;
    int tb = tgt[b];
    float acc = b1[j];
    const float* vv = v2 + (b * 102 + tb) * 16;
    const float* wr = w1 + (tb * 16) * 512 + j;
#pragma unroll
    for (int d = 0; d < 16; ++d) acc += vv[d] * wr[d * 512];
    h1[b * 512 + j] = fmaxf(acc, 0.f);
  }
}

__global__ void k_fc2(const float* __restrict__ h1, const float* __restrict__ w2,
                      const float* __restrict__ b2, float* __restrict__ h2T) {
  int j = blockIdx.x * 128 + threadIdx.x;  // < 1024
  int bq = blockIdx.y;
  float acc[4];
#pragma unroll
  for (int bi = 0; bi < 4; ++bi) acc[bi] = b2[j];
  for (int k = 0; k < 512; ++k) {
    float wv = w2[k * 1024 + j];
#pragma unroll
    for (int bi = 0; bi < 4; ++bi) acc[bi] += h1[(bq * 4 + bi) * 512 + k] * wv;
  }
  float4 o;
  o.x = fmaxf(acc[0], 0.f); o.y = fmaxf(acc[1], 0.f);
  o.z = fmaxf(acc[2], 0.f); o.w = fmaxf(acc[3], 0.f);
  *(float4*)(h2T + j * 32 + bq * 4) = o;
}

__global__ void k_fc3(const float* __restrict__ h2T, const float* __restrict__ w3,
                      const float* __restrict__ b3, float* __restrict__ out) {
  int j = blockIdx.x * 128 + threadIdx.x;  // < 37632
  int bq = blockIdx.y;
  float acc[8];
  float bv = b3[j];
#pragma unroll
  for (int i = 0; i < 8; ++i) acc[i] = bv;
  for (int k = 0; k < 1024; ++k) {
    float wv = w3[(size_t)k * 37632 + j];
    const float4* hp = (const float4*)(h2T + k * 32 + bq * 8);
    float4 ha = hp[0], hb = hp[1];
    acc[0] += ha.x * wv; acc[1] += ha.y * wv; acc[2] += ha.z * wv; acc[3] += ha.w * wv;
    acc[4] += hb.x * wv; acc[5] += hb.y * wv; acc[6] += hb.z * wv; acc[7] += hb.w * wv;
  }
#pragma unroll
  for (int i = 0; i < 8; ++i) {
    float sg = 1.0f / (1.0f + __expf(-acc[i]));
    out[52224 + (size_t)(bq * 8 + i) * 37632 + j] = sg;
  }
}

// ---------------- host ----------------
extern "C" void kernel_launch(void* const* d_in, const int* in_sizes, int n_in,
                              void* d_out, int out_size, void* d_ws, size_t ws_size,
                              hipStream_t stream) {
  const float* x       = (const float*)d_in[0];
  const int*   targets = (const int*)d_in[1];
  const float* conv1_w = (const float*)d_in[2];
  const float* conv1_b = (const float*)d_in[3];
  const float* pc_w    = (const float*)d_in[4];
  const float* pc_b    = (const float*)d_in[5];
  const float* W       = (const float*)d_in[6];
  const float* fc1_w   = (const float*)d_in[7];
  const float* fc1_b   = (const float*)d_in[8];
  const float* fc2_w   = (const float*)d_in[9];
  const float* fc2_b   = (const float*)d_in[10];
  const float* fc3_w   = (const float*)d_in[11];
  const float* fc3_b   = (const float*)d_in[12];
  float* out = (float*)d_out;
  float* ws = (float*)d_ws;

  float* FEAT = ws + OFF_FEAT;
  float* C1WT = ws + OFF_C1WT;
  unsigned short* PCWB = (unsigned short*)(ws + OFF_PCWT);
  float* PCP  = ws + OFF_PCP;
  float* PC2  = ws + OFF_PC2;
  float* U2   = ws + OFF_U2;
  unsigned short* WB = (unsigned short*)(ws + OFF_FEAT);
  unsigned char* WB2Q = (unsigned char*)(ws + OFF_WB2Q);
  __half* CT  = (__half*)(ws + OFF_CT);
  float* S    = ws + OFF_S;
  float* V0   = ws + OFF_V0;
  float* V1   = ws + OFF_V1;
  unsigned char* VSQ = (unsigned char*)(ws + OFF_VSQ);
  float* H1   = ws + OFF_H1;
  float* H2T  = ws + OFF_H2T;

  // weight prep
  k_wtrans<<<dim3(6, 4), 256, 0, stream>>>(conv1_w, C1WT, 256, 363);
  k_mkB<<<dim3(256), 256, 0, stream>>>(pc_w, PCWB);

  // conv1 + relu
  k_conv1<0><<<dim3(34 * 32), 256, 0, stream>>>(x, C1WT, conv1_b, FEAT);
  k_conv1<3><<<dim3(34 * 32), 256, 0, stream>>>(x, C1WT, conv1_b, FEAT);

  // primary caps conv + reduce + bias + squash
  k_pc2<<<dim3(41, 8), 256, 0, stream>>>(FEAT, PCWB, PCP);
  k_pcreduce<<<dim3(2592), 256, 0, stream>>>(PCP, pc_b, PC2);
  k_squash<<<dim3(324), 256, 0, stream>>>(PC2, U2);

  // routing packs (conv-phase buffers now dead)
  k_mkWb<<<dim3(16537), 256, 0, stream>>>(W, WB);
  k_mkWq<<<dim3(1033), 256, 0, stream>>>(W, WB2Q);

  // ---- routing ----
  hipMemsetAsync(S, 0, 52224 * sizeof(float), stream);
  k_B2<false><<<dim3(102, 8), 256, 0, stream>>>(WB, U2, nullptr, S);
  k_R<<<dim3(13), 256, 0, stream>>>(S, 1.0f / 102.0f, V0, nullptr, VSQ);

  k_A2<<<dim3(648), 128, 0, stream>>>(WB2Q, U2, VSQ, CT);
  hipMemsetAsync(S, 0, 52224 * sizeof(float), stream);
  k_B2<true><<<dim3(102, 8), 256, 0, stream>>>(WB, U2, CT, S);
  k_R<<<dim3(13), 256, 0, stream>>>(S, 1.0f, V1, V0, VSQ);  // vsq = v0+v1

  k_A2<<<dim3(648), 128, 0, stream>>>(WB2Q, U2, VSQ, CT);
  hipMemsetAsync(S, 0, 52224 * sizeof(float), stream);
  k_B2<true><<<dim3(102, 8), 256, 0, stream>>>(WB, U2, CT, S);
  k_R<<<dim3(13), 256, 0, stream>>>(S, 1.0f, out, nullptr, nullptr);

  // ---- reconstruction ----
  k_fc1<<<dim3(4, 8), 128, 0, stream>>>(out, targets, fc1_w, fc1_b, H1);
  k_fc2<<<dim3(8, 8), 128, 0, stream>>>(H1, fc2_w, fc2_b, H2T);
  k_fc3<<<dim3(294, 4), 128, 0, stream>>>(H2T, fc3_w, fc3_b, out);
}

// Round 5
// 758.808 us; speedup vs baseline: 3.2945x; 1.2436x over previous
//
#include <hip/hip_runtime.h>
#include <hip/hip_fp16.h>
#include <math.h>

// ---------------- sizes ----------------
#define B32   32
#define OCLS  102
#define NCAPS 2592
#define DIN   8
#define DOUT  16

// ---------------- ws map (floats) ----------------
// phase 1 (conv/pc): FEAT2 C1WB PCWB PCP PC2 U2
// phase 2 (routing): WB(bf16) [0,16933888) overlays FEAT2/C1WB/PCWB/PCP-low
//                    WB2Q(fp8) [16933888,25400832) overlays PCP-high/PC2
// phase 3 (recon):   FC3P overlays U2+CT (dead after last k_B2)
#define OFF_FEAT   0u               // feat2[b][h][co][w36]: 32*34*256*36 = 10,027,008
#define OFF_C1WT   10027008u        // bf16 conv1 pack: 3*256*128 ush = 49,152 fl
#define OFF_PCWT   10119936u        // bf16 pc pack: 256*256*104 ush
#define OFF_PCP    15428352u        // 8*32*81*256  =  5,308,416
#define OFF_PC2    20736768u        // 32*81*256    =    663,552
#define OFF_WB2Q   16933888u        // fp8 W pack [o][n][i][d]: 33,867,776 B
#define OFF_U2     25400832u        // 32*2592*8    =    663,552
#define OFF_CT     26064384u        // fp16 c[o][n][b]: 8,460,288 halfs
#define OFF_FC3P   25400832u        // fc3 partials 4*32*37632 = 4,816,896 (overlay U2+CT)
#define OFF_S      30294528u        // 32*102*16
#define OFF_V0     30346752u
#define OFF_V1     30398976u
#define OFF_VSQ    30451200u        // fp8 vsum[o][b][d]: 52,224 B
#define OFF_H1     30464256u        // 32*512
#define OFF_H2T    30480640u        // 1024*32  -> end 30,513,408

typedef __attribute__((ext_vector_type(8))) short short8;
typedef __attribute__((ext_vector_type(4))) float f32x4;
typedef long long i64;

__device__ __forceinline__ unsigned short f2b(float f) {
  union { float f; unsigned u; } v; v.f = f;
  unsigned r = v.u + 0x7fffu + ((v.u >> 16) & 1u);
  return (unsigned short)(r >> 16);
}

// float -> OCP e4m3fn (RNE)
__device__ __forceinline__ unsigned char f2q(float f) {
  float a = fabsf(f);
  unsigned char s = (f < 0.f) ? 0x80 : 0;
  if (!(a < 448.f)) return s | 0x7E;
  if (a < 0.0009765625f) return s;
  if (a < 0.015625f) {
    int q = (int)rintf(a * 512.f);
    if (q >= 8) return s | 0x08;
    return s | (unsigned char)q;
  }
  int eb;
  frexpf(a, &eb);
  int E = eb - 1;
  float m = ldexpf(a, -E);
  int mm = (int)rintf(m * 8.f);
  if (mm >= 16) { mm = 8; E += 1; }
  return s | (unsigned char)(((E + 7) << 3) | (mm - 8));
}

// ---------------- conv1_w -> bf16 [ci][co][128] (taps 0..120 real, pad 0) ------
__global__ void k_mkC1B(const float* __restrict__ conv1_w,
                        unsigned short* __restrict__ C1WB) {
  int co = blockIdx.x;  // 256
  int t = threadIdx.x;  // 128
#pragma unroll
  for (int ci = 0; ci < 3; ++ci) {
    float v = (t < 121) ? conv1_w[co * 363 + ci * 121 + t] : 0.f;
    C1WB[(ci * 256 + co) * 128 + t] = f2b(v);
  }
}

// ---------------- pc_w repack -> bf16 [ci][co][104] ----------------
__global__ void k_mkB(const float* __restrict__ pc_w, unsigned short* __restrict__ PCWB) {
  int co = blockIdx.x;
  for (int e = threadIdx.x; e < 20736; e += 256) {
    int ci = e / 81, tap = e - ci * 81;
    PCWB[(size_t)ci * 26624 + co * 104 + tap] = f2b(pc_w[(size_t)co * 20736 + e]);
  }
  int ci = threadIdx.x;
  for (int tap = 81; tap < 104; ++tap)
    PCWB[(size_t)ci * 26624 + co * 104 + tap] = 0;
}

// ---------------- routing W -> bf16 Wb[o][n][d][i] (same element order) --------
__global__ void k_mkWb(const float* __restrict__ W, unsigned short* __restrict__ Wb) {
  size_t i = ((size_t)blockIdx.x * 256 + threadIdx.x) * 8;
  const float4* p = (const float4*)(W + i);
  float4 a = p[0], b = p[1];
  unsigned u0 = (unsigned)f2b(a.x) | ((unsigned)f2b(a.y) << 16);
  unsigned u1 = (unsigned)f2b(a.z) | ((unsigned)f2b(a.w) << 16);
  unsigned u2 = (unsigned)f2b(b.x) | ((unsigned)f2b(b.y) << 16);
  unsigned u3 = (unsigned)f2b(b.z) | ((unsigned)f2b(b.w) << 16);
  *(uint4*)(Wb + i) = make_uint4(u0, u1, u2, u3);
}

// ---------------- routing W -> fp8 Wq[o][n][i][d] (d/i transposed) ----------------
__global__ void k_mkWq(const float* __restrict__ W, unsigned char* __restrict__ Wq) {
  int on = blockIdx.x * 256 + threadIdx.x;
  if (on >= 102 * 2592) return;
  const float* src = W + (size_t)on * 128;
  unsigned words[8][4];
#pragma unroll
  for (int i = 0; i < 8; ++i)
#pragma unroll
    for (int w = 0; w < 4; ++w) words[i][w] = 0;
#pragma unroll
  for (int d = 0; d < 16; ++d) {
    const float4* p = (const float4*)(src + d * 8);
    float4 a = p[0], b = p[1];
    float vals[8] = {a.x, a.y, a.z, a.w, b.x, b.y, b.z, b.w};
#pragma unroll
    for (int i = 0; i < 8; ++i)
      words[i][d >> 2] |= ((unsigned)f2q(vals[i])) << ((d & 3) * 8);
  }
  uint4* dst = (uint4*)(Wq + (size_t)on * 128);
#pragma unroll
  for (int i = 0; i < 8; ++i)
    dst[i] = make_uint4(words[i][0], words[i][1], words[i][2], words[i][3]);
}

// ---------------- conv1 via bf16 MFMA implicit-im2col ----------------
// block = (b,ho); M=34 wo (pad 48), N=256 co, K=3 ci-chunks of 121->128.
// LDS lA[48][128], lB[256][128] bf16 with T2 XOR-swizzle (16B units ^ row&7)
// to kill the 256B-pitch bank conflict. Output staged to LDS -> contiguous
// float4 writes into feat2[b][ho][co][36].
__global__ __launch_bounds__(256) void k_c1m(const float* __restrict__ x,
                                             const unsigned short* __restrict__ C1WB,
                                             const float* __restrict__ bias,
                                             float* __restrict__ feat2) {
  __shared__ unsigned short sh[48 * 128 + 256 * 128];
  unsigned short* lA = sh;
  unsigned short* lB = sh + 48 * 128;
  float* obuf = (float*)(sh + 48 * 128);  // reused in epilogue

  int bx = blockIdx.x;  // 1088
  int b = bx / 34, ho = bx % 34;
  int t = threadIdx.x;
  int lane = t & 63, wv = t >> 6;
  int l15 = lane & 15, lh = lane >> 4;
  int rx = l15 & 7;

  {
    uint4 zz = make_uint4(0, 0, 0, 0);
    uint4* z = (uint4*)lA;
    for (int i = t; i < 48 * 128 / 8; i += 256) z[i] = zz;
  }
  __syncthreads();

  f32x4 acc[3][4];
#pragma unroll
  for (int mf = 0; mf < 3; ++mf)
#pragma unroll
    for (int nf = 0; nf < 4; ++nf) acc[mf][nf] = (f32x4){0.f, 0.f, 0.f, 0.f};

#pragma unroll 1
  for (int ci = 0; ci < 3; ++ci) {
    // stage B (swizzled dest)
    {
      const uint4* Bsrc = (const uint4*)(C1WB + ci * 32768);
#pragma unroll
      for (int i = 0; i < 16; ++i) {
        int f = i * 256 + t;
        int row = f >> 4, cu = f & 15;
        ((uint4*)lB)[row * 16 + (cu ^ (row & 7))] = Bsrc[f];
      }
    }
    // gather A: 374 tasks (kh,wo), 11 taps each (swizzled dest)
    for (int tk = t; tk < 374; tk += 256) {
      int kh = tk / 34, wo = tk - kh * 34;
      const float* src = x + ((size_t)(b * 3 + ci) * 112 + ho * 3 + kh) * 112 + wo * 3;
#pragma unroll
      for (int j = 0; j < 11; ++j) {
        int tap = kh * 11 + j;
        int cu = tap >> 3;
        lA[wo * 128 + (((cu ^ (wo & 7)) << 3) | (tap & 7))] = f2b(src[j]);
      }
    }
    __syncthreads();

#pragma unroll
    for (int s = 0; s < 4; ++s) {
      int cub = ((s * 4 + lh) ^ rx) << 3;
      short8 a0 = *(const short8*)(lA + (0 + l15) * 128 + cub);
      short8 a1 = *(const short8*)(lA + (16 + l15) * 128 + cub);
      short8 a2 = *(const short8*)(lA + (32 + l15) * 128 + cub);
      short8 b0 = *(const short8*)(lB + (wv * 64 + 0 + l15) * 128 + cub);
      short8 b1 = *(const short8*)(lB + (wv * 64 + 16 + l15) * 128 + cub);
      short8 b2 = *(const short8*)(lB + (wv * 64 + 32 + l15) * 128 + cub);
      short8 b3 = *(const short8*)(lB + (wv * 64 + 48 + l15) * 128 + cub);
      acc[0][0] = __builtin_amdgcn_mfma_f32_16x16x32_bf16(a0, b0, acc[0][0], 0, 0, 0);
      acc[0][1] = __builtin_amdgcn_mfma_f32_16x16x32_bf16(a0, b1, acc[0][1], 0, 0, 0);
      acc[0][2] = __builtin_amdgcn_mfma_f32_16x16x32_bf16(a0, b2, acc[0][2], 0, 0, 0);
      acc[0][3] = __builtin_amdgcn_mfma_f32_16x16x32_bf16(a0, b3, acc[0][3], 0, 0, 0);
      acc[1][0] = __builtin_amdgcn_mfma_f32_16x16x32_bf16(a1, b0, acc[1][0], 0, 0, 0);
      acc[1][1] = __builtin_amdgcn_mfma_f32_16x16x32_bf16(a1, b1, acc[1][1], 0, 0, 0);
      acc[1][2] = __builtin_amdgcn_mfma_f32_16x16x32_bf16(a1, b2, acc[1][2], 0, 0, 0);
      acc[1][3] = __builtin_amdgcn_mfma_f32_16x16x32_bf16(a1, b3, acc[1][3], 0, 0, 0);
      acc[2][0] = __builtin_amdgcn_mfma_f32_16x16x32_bf16(a2, b0, acc[2][0], 0, 0, 0);
      acc[2][1] = __builtin_amdgcn_mfma_f32_16x16x32_bf16(a2, b1, acc[2][1], 0, 0, 0);
      acc[2][2] = __builtin_amdgcn_mfma_f32_16x16x32_bf16(a2, b2, acc[2][2], 0, 0, 0);
      acc[2][3] = __builtin_amdgcn_mfma_f32_16x16x32_bf16(a2, b3, acc[2][3], 0, 0, 0);
    }
    __syncthreads();
  }

  // epilogue: bias+relu -> obuf[co][36] -> contiguous float4 store
  float bv[4];
#pragma unroll
  for (int nf = 0; nf < 4; ++nf) bv[nf] = bias[wv * 64 + nf * 16 + l15];
#pragma unroll
  for (int mf = 0; mf < 3; ++mf)
#pragma unroll
    for (int nf = 0; nf < 4; ++nf)
#pragma unroll
      for (int r = 0; r < 4; ++r) {
        int wo = mf * 16 + lh * 4 + r;
        if (wo < 36)
          obuf[(wv * 64 + nf * 16 + l15) * 36 + wo] = fmaxf(acc[mf][nf][r] + bv[nf], 0.f);
      }
  __syncthreads();
  float4* dst = (float4*)(feat2 + (size_t)bx * 9216);
  const float4* srcb = (const float4*)obuf;
#pragma unroll
  for (int i = 0; i < 9; ++i) dst[i * 256 + t] = srcb[i * 256 + t];
}

// ---------------- primary caps conv: bf16 MFMA implicit-im2col GEMM ----------------
__global__ __launch_bounds__(256) void k_pc2(const float* __restrict__ feat2,
                                             const unsigned short* __restrict__ PCWB,
                                             float* __restrict__ pcp) {
  __shared__ unsigned short sh[64 * 104 + 256 * 104];
  unsigned short* lA = sh;
  unsigned short* lB = sh + 64 * 104;

  int mb = blockIdx.x, kc = blockIdx.y;
  int t = threadIdx.x;
  int lane = t & 63, wv = t >> 6;
  int l15 = lane & 15, lh = lane >> 4;

  {
    uint4 zz = make_uint4(0, 0, 0, 0);
    uint4* z = (uint4*)sh;
    for (int i = t; i < (64 * 104 + 256 * 104) / 8; i += 256) z[i] = zz;
  }
  __syncthreads();

  f32x4 acc[4][4];
#pragma unroll
  for (int mf = 0; mf < 4; ++mf)
#pragma unroll
    for (int nf = 0; nf < 4; ++nf) acc[mf][nf] = (f32x4){0.f, 0.f, 0.f, 0.f};

  const unsigned short* arow = lA + l15 * 104 + lh * 8;
  const unsigned short* brow = lB + (wv * 64 + l15) * 104 + lh * 8;

#pragma unroll 1
  for (int cil = 0; cil < 32; ++cil) {
    int ci = kc * 32 + cil;
    {
      const unsigned short* Bsrc = PCWB + (size_t)ci * 26624;
#pragma unroll
      for (int i = 0; i < 13; ++i) {
        int f = i * 256 + t;
        ((uint4*)lB)[f] = *(const uint4*)(Bsrc + (size_t)f * 8);
      }
    }
    for (int task = t; task < 576; task += 256) {
      int m = task / 9, kh = task - m * 9;
      int gm = mb * 64 + m;
      if (gm < 2592) {
        int b = gm / 81, p = gm - b * 81;
        int ho = p / 9, wo = p - ho * 9;
        const float* src = feat2 + ((size_t)(b * 34 + ho * 3 + kh) * 256 + ci) * 36 + wo * 3;
        unsigned short* dstp = lA + m * 104 + kh * 9;
#pragma unroll
        for (int j = 0; j < 9; ++j) dstp[j] = f2b(src[j]);
      }
    }
    __syncthreads();

#pragma unroll
    for (int s = 0; s < 3; ++s) {
      short8 a0 = *(const short8*)(arow + s * 32);
      short8 a1 = *(const short8*)(arow + 16 * 104 + s * 32);
      short8 a2 = *(const short8*)(arow + 32 * 104 + s * 32);
      short8 a3 = *(const short8*)(arow + 48 * 104 + s * 32);
      short8 b0 = *(const short8*)(brow + s * 32);
      short8 b1 = *(const short8*)(brow + 16 * 104 + s * 32);
      short8 b2 = *(const short8*)(brow + 32 * 104 + s * 32);
      short8 b3 = *(const short8*)(brow + 48 * 104 + s * 32);
      acc[0][0] = __builtin_amdgcn_mfma_f32_16x16x32_bf16(a0, b0, acc[0][0], 0, 0, 0);
      acc[0][1] = __builtin_amdgcn_mfma_f32_16x16x32_bf16(a0, b1, acc[0][1], 0, 0, 0);
      acc[0][2] = __builtin_amdgcn_mfma_f32_16x16x32_bf16(a0, b2, acc[0][2], 0, 0, 0);
      acc[0][3] = __builtin_amdgcn_mfma_f32_16x16x32_bf16(a0, b3, acc[0][3], 0, 0, 0);
      acc[1][0] = __builtin_amdgcn_mfma_f32_16x16x32_bf16(a1, b0, acc[1][0], 0, 0, 0);
      acc[1][1] = __builtin_amdgcn_mfma_f32_16x16x32_bf16(a1, b1, acc[1][1], 0, 0, 0);
      acc[1][2] = __builtin_amdgcn_mfma_f32_16x16x32_bf16(a1, b2, acc[1][2], 0, 0, 0);
      acc[1][3] = __builtin_amdgcn_mfma_f32_16x16x32_bf16(a1, b3, acc[1][3], 0, 0, 0);
      acc[2][0] = __builtin_amdgcn_mfma_f32_16x16x32_bf16(a2, b0, acc[2][0], 0, 0, 0);
      acc[2][1] = __builtin_amdgcn_mfma_f32_16x16x32_bf16(a2, b1, acc[2][1], 0, 0, 0);
      acc[2][2] = __builtin_amdgcn_mfma_f32_16x16x32_bf16(a2, b2, acc[2][2], 0, 0, 0);
      acc[2][3] = __builtin_amdgcn_mfma_f32_16x16x32_bf16(a2, b3, acc[2][3], 0, 0, 0);
      acc[3][0] = __builtin_amdgcn_mfma_f32_16x16x32_bf16(a3, b0, acc[3][0], 0, 0, 0);
      acc[3][1] = __builtin_amdgcn_mfma_f32_16x16x32_bf16(a3, b1, acc[3][1], 0, 0, 0);
      acc[3][2] = __builtin_amdgcn_mfma_f32_16x16x32_bf16(a3, b2, acc[3][2], 0, 0, 0);
      acc[3][3] = __builtin_amdgcn_mfma_f32_16x16x32_bf16(a3, b3, acc[3][3], 0, 0, 0);
    }
    __syncthreads();
  }

#pragma unroll
  for (int mf = 0; mf < 4; ++mf) {
    int gm = mb * 64 + mf * 16 + lh * 4;
    if (gm < 2592) {
      float* dst = pcp + (size_t)kc * 663552 + (size_t)gm * 256 + wv * 64 + l15;
#pragma unroll
      for (int nf = 0; nf < 4; ++nf)
#pragma unroll
        for (int r = 0; r < 4; ++r)
          dst[(size_t)r * 256 + nf * 16] = acc[mf][nf][r];
    }
  }
}

// sum 8 ci-chunk partials + bias
__global__ void k_pcreduce(const float* __restrict__ pcp,
                           const float* __restrict__ pcb,
                           float* __restrict__ pc2) {
  int i = blockIdx.x * 256 + threadIdx.x;
  float s = pcb[i & 255];
#pragma unroll
  for (int c = 0; c < 8; ++c) s += pcp[c * 663552 + i];
  pc2[i] = s;
}

// squash u (dim 8) -> u2[b][n][i]
__global__ void k_squash(const float* __restrict__ pc2, float* __restrict__ u2) {
  int t = blockIdx.x * 256 + threadIdx.x;  // < 82944
  int b = t / 2592, n = t - b * 2592;
  float v[8];
  float sq = 0.f;
#pragma unroll
  for (int i = 0; i < 8; ++i) {
    int f = n * 8 + i;
    int co = f / 81, p = f - co * 81;
    v[i] = pc2[(b * 81 + p) * 256 + co];
    sq += v[i] * v[i];
  }
  float sc = (sq / (1.f + sq)) / sqrtf(sq + 1e-8f);
#pragma unroll
  for (int i = 0; i < 8; ++i) u2[t * 8 + i] = v[i] * sc;
}

// ---------------- routing kernel A (fp8 MFMA): logits + softmax -> cT ----------------
__global__ __launch_bounds__(128) void k_A2(const unsigned char* __restrict__ Wq,
                                            const float* __restrict__ u2,
                                            const unsigned char* __restrict__ vq,
                                            __half* __restrict__ cT) {
  __shared__ __half Eld[102 * 2 * 2 * 32];
  int nb = blockIdx.x;  // 648
  int t = threadIdx.x, wv = t >> 6, lane = t & 63;
  int l15 = lane & 15, g = lane >> 4;
  int n0 = nb * 4 + 2 * wv;
  int nl = g >> 1, ih = (g & 1) * 4;

  float4 u0 = *(const float4*)(u2 + (((size_t)l15 * 2592 + n0 + nl) * 8 + ih));
  float4 u1 = *(const float4*)(u2 + (((size_t)(l15 + 16) * 2592 + n0 + nl) * 8 + ih));

  int nlA = l15 >> 3, iA = l15 & 7;
  const unsigned char* Ap = Wq + (((size_t)(n0 + nlA)) * 8 + iA) * 16 + (g & 1) * 8;
  const unsigned char* B0p = vq + (size_t)l15 * 16 + (g & 1) * 8;
  bool act = (g < 2);

  float den0 = 0.f, den1 = 0.f;
#pragma unroll 2
  for (int o = 0; o < 102; ++o) {
    i64 a = 0, b0 = 0, b1 = 0;
    if (act) {
      a  = *(const i64*)(Ap + (size_t)o * 331776);
      b0 = *(const i64*)(B0p + (size_t)o * 512);
      b1 = *(const i64*)(B0p + (size_t)o * 512 + 256);
    }
    f32x4 d0 = {0.f, 0.f, 0.f, 0.f}, d1 = {0.f, 0.f, 0.f, 0.f};
    d0 = __builtin_amdgcn_mfma_f32_16x16x32_fp8_fp8(a, b0, d0, 0, 0, 0);
    d1 = __builtin_amdgcn_mfma_f32_16x16x32_fp8_fp8(a, b1, d1, 0, 0, 0);
    float p0 = d0[0] * u0.x + d0[1] * u0.y + d0[2] * u0.z + d0[3] * u0.w;
    float p1 = d1[0] * u1.x + d1[1] * u1.y + d1[2] * u1.z + d1[3] * u1.w;
    p0 += __shfl_xor(p0, 16);
    p1 += __shfl_xor(p1, 16);
    float e0 = __expf(p0), e1 = __expf(p1);
    den0 += e0; den1 += e1;
    if ((g & 1) == 0) {
      int base = (o * 2 + wv) * 64 + (g >> 1) * 16 + l15;
      Eld[base] = __float2half(e0);
      Eld[base + 32] = __float2half(e1);
    }
  }
  float r0 = 1.0f / den0, r1 = 1.0f / den1;
  if ((g & 1) == 0) {
    for (int o = 0; o < 102; ++o) {
      int base = (o * 2 + wv) * 64 + (g >> 1) * 16 + l15;
      float c0 = __half2float(Eld[base]) * r0;
      float c1 = __half2float(Eld[base + 32]) * r1;
      __half* dst = cT + ((size_t)o * 2592 + n0 + (g >> 1)) * 32 + l15;
      dst[0] = __float2half(c0);
      dst[16] = __float2half(c1);
    }
  }
}

// ---------------- routing kernel B (bf16 MFMA) ----------------
__device__ __forceinline__ short8 cu_pack(float c, float4 a, float4 b) {
  short8 r;
  r[0] = (short)f2b(c * a.x); r[1] = (short)f2b(c * a.y);
  r[2] = (short)f2b(c * a.z); r[3] = (short)f2b(c * a.w);
  r[4] = (short)f2b(c * b.x); r[5] = (short)f2b(c * b.y);
  r[6] = (short)f2b(c * b.z); r[7] = (short)f2b(c * b.w);
  return r;
}

template <bool HASC>
__global__ __launch_bounds__(256) void k_B2(const unsigned short* __restrict__ Wb,
                                            const float* __restrict__ u2,
                                            const __half* __restrict__ cT,
                                            float* __restrict__ s) {
  int o = blockIdx.x, kc = blockIdx.y;
  int t = threadIdx.x, lane = t & 63, wv = t >> 6;
  int l15 = lane & 15, h = lane >> 4;

  f32x4 acc0 = {0.f, 0.f, 0.f, 0.f}, acc1 = {0.f, 0.f, 0.f, 0.f};

#pragma unroll 1
  for (int st = wv; st < 81; st += 4) {
    int n = kc * 324 + st * 4 + h;
    short8 af = *(const short8*)(Wb + (((size_t)o * 2592 + n) * 16 + l15) * 8);

    const float4* u0p = (const float4*)(u2 + ((size_t)l15 * 2592 + n) * 8);
    float4 u0a = u0p[0], u0b = u0p[1];
    const float4* u1p = (const float4*)(u2 + ((size_t)(l15 + 16) * 2592 + n) * 8);
    float4 u1a = u1p[0], u1b = u1p[1];

    float c0 = 1.0f, c1 = 1.0f;
    if (HASC) {
      const __half* cp = cT + ((size_t)o * 2592 + n) * 32;
      c0 = __half2float(cp[l15]);
      c1 = __half2float(cp[l15 + 16]);
    }
    short8 bf0 = cu_pack(c0, u0a, u0b);
    short8 bf1 = cu_pack(c1, u1a, u1b);

    acc0 = __builtin_amdgcn_mfma_f32_16x16x32_bf16(af, bf0, acc0, 0, 0, 0);
    acc1 = __builtin_amdgcn_mfma_f32_16x16x32_bf16(af, bf1, acc1, 0, 0, 0);
  }

#pragma unroll
  for (int r = 0; r < 4; ++r) {
    atomicAdd(s + ((size_t)l15 * 102 + o) * 16 + h * 4 + r, acc0[r]);
    atomicAdd(s + ((size_t)(l15 + 16) * 102 + o) * 16 + h * 4 + r, acc1[r]);
  }
}

// ---------------- squash v (dim 16); optional fp8 vsum[o][b][d] output -----------
__global__ void k_R(const float* __restrict__ s, float scale,
                    float* __restrict__ vout, const float* __restrict__ addin,
                    unsigned char* __restrict__ vsq) {
  int t = blockIdx.x * 256 + threadIdx.x;
  if (t >= 3264) return;
  const float* sp = s + t * 16;
  float r[16];
  float sq = 0.f;
#pragma unroll
  for (int d = 0; d < 16; ++d) {
    r[d] = sp[d] * scale;
    sq += r[d] * r[d];
  }
  float sc = (sq / (1.f + sq)) / sqrtf(sq + 1e-8f);
  float vv[16];
#pragma unroll
  for (int d = 0; d < 16; ++d) {
    vv[d] = r[d] * sc;
    vout[t * 16 + d] = vv[d];
  }
  if (vsq) {
    int b = t / 102, o = t - b * 102;
    unsigned words[4] = {0, 0, 0, 0};
#pragma unroll
    for (int d = 0; d < 16; ++d) {
      float w = addin ? (addin[t * 16 + d] + vv[d]) : vv[d];
      words[d >> 2] |= ((unsigned)f2q(w)) << ((d & 3) * 8);
    }
    *(uint4*)(vsq + ((size_t)o * 32 + b) * 16) =
        make_uint4(words[0], words[1], words[2], words[3]);
  }
}

// ---------------- fc chain ----------------
__global__ void k_fc1(const float* __restrict__ v2, const int* __restrict__ tgt,
                      const float* __restrict__ w1, const float* __restrict__ b1,
                      float* __restrict__ h1) {
  int j = blockIdx.x * 128 + threadIdx.x;  // < 512
  int bq = blockIdx.y;
#pragma unroll
  for (int bi = 0; bi < 4; ++bi) {
    int b = bq * 4 + bi;
    int tb = tgt[b];
    float acc = b1[j];
    const float* vv = v2 + (b * 102 + tb) * 16;
    const float* wr = w1 + (tb * 16) * 512 + j;
#pragma unroll
    for (int d = 0; d < 16; ++d) acc += vv[d] * wr[d * 512];
    h1[b * 512 + j] = fmaxf(acc, 0.f);
  }
}

__global__ void k_fc2(const float* __restrict__ h1, const float* __restrict__ w2,
                      const float* __restrict__ b2, float* __restrict__ h2T) {
  int j = blockIdx.x * 128 + threadIdx.x;  // < 1024
  int bq = blockIdx.y;
  float acc[4];
#pragma unroll
  for (int bi = 0; bi < 4; ++bi) acc[bi] = b2[j];
  for (int k = 0; k < 512; ++k) {
    float wv = w2[k * 1024 + j];
#pragma unroll
    for (int bi = 0; bi < 4; ++bi) acc[bi] += h1[(bq * 4 + bi) * 512 + k] * wv;
  }
  float4 o;
  o.x = fmaxf(acc[0], 0.f); o.y = fmaxf(acc[1], 0.f);
  o.z = fmaxf(acc[2], 0.f); o.w = fmaxf(acc[3], 0.f);
  *(float4*)(h2T + j * 32 + bq * 4) = o;
}

// fc3 split-K: ky owns k-range of 256; w3 read exactly once across grid
__global__ void k_fc3a(const float* __restrict__ h2T, const float* __restrict__ w3,
                       float* __restrict__ p) {
  int j = blockIdx.x * 128 + threadIdx.x;  // 294*128 = 37632
  int ky = blockIdx.y;                     // 4
  float acc[32];
#pragma unroll
  for (int i = 0; i < 32; ++i) acc[i] = 0.f;
  int k0 = ky * 256;
  for (int k = k0; k < k0 + 256; ++k) {
    float wv = w3[(size_t)k * 37632 + j];
    const float4* hp = (const float4*)(h2T + k * 32);
#pragma unroll
    for (int q = 0; q < 8; ++q) {
      float4 h = hp[q];
      acc[q * 4 + 0] += h.x * wv; acc[q * 4 + 1] += h.y * wv;
      acc[q * 4 + 2] += h.z * wv; acc[q * 4 + 3] += h.w * wv;
    }
  }
#pragma unroll
  for (int i = 0; i < 32; ++i)
    p[((size_t)ky * 32 + i) * 37632 + j] = acc[i];
}

__global__ void k_fc3b(const float* __restrict__ p, const float* __restrict__ b3,
                       float* __restrict__ out) {
  int j = blockIdx.x * 256 + threadIdx.x;  // 147*256 = 37632
  float bv = b3[j];
#pragma unroll 1
  for (int b = 0; b < 32; ++b) {
    float s = bv + p[(size_t)b * 37632 + j] + p[(size_t)(32 + b) * 37632 + j] +
              p[(size_t)(64 + b) * 37632 + j] + p[(size_t)(96 + b) * 37632 + j];
    out[52224 + (size_t)b * 37632 + j] = 1.0f / (1.0f + __expf(-s));
  }
}

// ---------------- host ----------------
extern "C" void kernel_launch(void* const* d_in, const int* in_sizes, int n_in,
                              void* d_out, int out_size, void* d_ws, size_t ws_size,
                              hipStream_t stream) {
  const float* x       = (const float*)d_in[0];
  const int*   targets = (const int*)d_in[1];
  const float* conv1_w = (const float*)d_in[2];
  const float* conv1_b = (const float*)d_in[3];
  const float* pc_w    = (const float*)d_in[4];
  const float* pc_b    = (const float*)d_in[5];
  const float* W       = (const float*)d_in[6];
  const float* fc1_w   = (const float*)d_in[7];
  const float* fc1_b   = (const float*)d_in[8];
  const float* fc2_w   = (const float*)d_in[9];
  const float* fc2_b   = (const float*)d_in[10];
  const float* fc3_w   = (const float*)d_in[11];
  const float* fc3_b   = (const float*)d_in[12];
  float* out = (float*)d_out;
  float* ws = (float*)d_ws;

  float* FEAT2 = ws + OFF_FEAT;
  unsigned short* C1WB = (unsigned short*)(ws + OFF_C1WT);
  unsigned short* PCWB = (unsigned short*)(ws + OFF_PCWT);
  float* PCP  = ws + OFF_PCP;
  float* PC2  = ws + OFF_PC2;
  float* U2   = ws + OFF_U2;
  unsigned short* WB = (unsigned short*)(ws + OFF_FEAT);
  unsigned char* WB2Q = (unsigned char*)(ws + OFF_WB2Q);
  __half* CT  = (__half*)(ws + OFF_CT);
  float* FC3P = ws + OFF_FC3P;
  float* S    = ws + OFF_S;
  float* V0   = ws + OFF_V0;
  float* V1   = ws + OFF_V1;
  unsigned char* VSQ = (unsigned char*)(ws + OFF_VSQ);
  float* H1   = ws + OFF_H1;
  float* H2T  = ws + OFF_H2T;

  // weight prep
  k_mkC1B<<<dim3(256), 128, 0, stream>>>(conv1_w, C1WB);
  k_mkB<<<dim3(256), 256, 0, stream>>>(pc_w, PCWB);

  // conv1 + relu (bf16 MFMA)
  k_c1m<<<dim3(1088), 256, 0, stream>>>(x, C1WB, conv1_b, FEAT2);

  // primary caps conv + reduce + bias + squash
  k_pc2<<<dim3(41, 8), 256, 0, stream>>>(FEAT2, PCWB, PCP);
  k_pcreduce<<<dim3(2592), 256, 0, stream>>>(PCP, pc_b, PC2);
  k_squash<<<dim3(324), 256, 0, stream>>>(PC2, U2);

  // routing packs (conv-phase buffers now dead)
  k_mkWb<<<dim3(16537), 256, 0, stream>>>(W, WB);
  k_mkWq<<<dim3(1033), 256, 0, stream>>>(W, WB2Q);

  // ---- routing ----
  hipMemsetAsync(S, 0, 52224 * sizeof(float), stream);
  k_B2<false><<<dim3(102, 8), 256, 0, stream>>>(WB, U2, nullptr, S);
  k_R<<<dim3(13), 256, 0, stream>>>(S, 1.0f / 102.0f, V0, nullptr, VSQ);

  k_A2<<<dim3(648), 128, 0, stream>>>(WB2Q, U2, VSQ, CT);
  hipMemsetAsync(S, 0, 52224 * sizeof(float), stream);
  k_B2<true><<<dim3(102, 8), 256, 0, stream>>>(WB, U2, CT, S);
  k_R<<<dim3(13), 256, 0, stream>>>(S, 1.0f, V1, V0, VSQ);  // vsq = v0+v1

  k_A2<<<dim3(648), 128, 0, stream>>>(WB2Q, U2, VSQ, CT);
  hipMemsetAsync(S, 0, 52224 * sizeof(float), stream);
  k_B2<true><<<dim3(102, 8), 256, 0, stream>>>(WB, U2, CT, S);
  k_R<<<dim3(13), 256, 0, stream>>>(S, 1.0f, out, nullptr, nullptr);

  // ---- reconstruction ----
  k_fc1<<<dim3(4, 8), 128, 0, stream>>>(out, targets, fc1_w, fc1_b, H1);
  k_fc2<<<dim3(8, 8), 128, 0, stream>>>(H1, fc2_w, fc2_b, H2T);
  k_fc3a<<<dim3(294, 4), 128, 0, stream>>>(H2T, fc3_w, FC3P);
  k_fc3b<<<dim3(147), 256, 0, stream>>>(FC3P, fc3_b, out);
}